// Round 14
// baseline (1858.753 us; speedup 1.0000x reference)
//
#include <hip/hip_runtime.h>
#include <hip/hip_bf16.h>
#include <math.h>

typedef __hip_bfloat16 bf16;
typedef __attribute__((ext_vector_type(8))) short  bf16x8;
typedef __attribute__((ext_vector_type(4))) float  f32x4;

#define NT_ 8000
#define MT_ 16000
#define NA_ 25000
#define MA_ 50000
#define NROOT_ 256

// ---------------------------------------------------------------------------
struct Feat {
  const float* dtab; const int* didx; int dstride;
  const float* otab;
  const int* oidx0; int os0; int oo0;
  const int* oidx1; int os1; int oo1;
  const int* oidx2; int os2; int oo2;
  const float* bias;
};

// Fast HW-native transcendentals (v_exp_f32 + v_rcp_f32; rel err ~1e-6).
__device__ __forceinline__ float rcpf_(float x){ return __builtin_amdgcn_rcpf(x); }
__device__ __forceinline__ float sigm(float x){ return rcpf_(1.0f + __expf(-x)); }
__device__ __forceinline__ float tanh_f(float x){
  float t = __expf(2.0f*x);
  return 1.0f - 2.0f*rcpf_(t + 1.0f);
}

__device__ __forceinline__ float ubf(unsigned int u){ union{unsigned int i; float f;} x; x.i = u<<16; return x.f; }
__device__ __forceinline__ unsigned int pack2bf(float a, float b){
  bf16 x = __float2bfloat16(a), y = __float2bfloat16(b);
  unsigned short ux = *(unsigned short*)&x, uy = *(unsigned short*)&y;
  return (unsigned int)ux | ((unsigned int)uy<<16);
}
__device__ __forceinline__ short f2bf_s(float f){
  bf16 b = __float2bfloat16(f);
  return *(short*)&b;
}
__device__ __forceinline__ float bfs2f(short s){ return ubf((unsigned short)s); }

__device__ __forceinline__ void acc4(float4& v, const float* p){
  float4 t = *(const float4*)p;
  v.x+=t.x; v.y+=t.y; v.z+=t.z; v.w+=t.w;
}
__device__ __forceinline__ float4 feat_eval4(const Feat& f, int m, int n){
  float4 v = make_float4(0,0,0,0);
  if (f.bias) acc4(v, f.bias + n);
  if (f.dtab) acc4(v, f.dtab + (size_t)f.didx[(size_t)m*f.dstride]*256 + n);
  if (f.otab){
    acc4(v, f.otab + (size_t)(f.oidx0[(size_t)m*f.os0]+f.oo0)*256 + n);
    if (f.oidx1) acc4(v, f.otab + (size_t)(f.oidx1[(size_t)m*f.os1]+f.oo1)*256 + n);
    if (f.oidx2) acc4(v, f.otab + (size_t)(f.oidx2[(size_t)m*f.os2]+f.oo2)*256 + n);
  }
  return v;
}
__device__ __forceinline__ float feat_eval(const Feat& f, int m, int n){
  float v = 0.0f;
  if (f.bias) v += f.bias[n];
  if (f.dtab) v += f.dtab[(size_t)f.didx[(size_t)m*f.dstride]*256 + n];
  if (f.otab){
    v += f.otab[((size_t)(f.oidx0[(size_t)m*f.os0]+f.oo0))*256 + n];
    if (f.oidx1) v += f.otab[((size_t)(f.oidx1[(size_t)m*f.os1]+f.oo1))*256 + n];
    if (f.oidx2) v += f.otab[((size_t)(f.oidx2[(size_t)m*f.os2]+f.oo2))*256 + n];
  }
  return v;
}

// ---------------------------------------------------------------------------
__global__ void k_aidx(const int* __restrict__ g_fnode, const int* __restrict__ g_fmess,
                       int* __restrict__ aidx, int M){
  int m = blockIdx.x*blockDim.x + threadIdx.x;
  if (m<M) aidx[m] = g_fnode[g_fmess[(size_t)m*4]];
}

// Batched weight split/swizzle.
struct SJob { const float* src; short* dst; int nrow; int pad; };
struct SJobs { SJob j[26]; };
__global__ void k_splitw_b(SJobs js){
  SJob jb = js.j[blockIdx.y];
  int idx = blockIdx.x*256 + threadIdx.x;
  if (idx >= jb.nrow*256) return;
  int k = idx>>8, n = idx&255;
  float w = jb.src[idx];
  int base = (((k>>5)*16 + (n>>4))<<10) + (((n&15) + (((k>>3)&3)<<4))<<4) + (k&7);
  short h = f2bf_s(w);
  jb.dst[base]   = h;
  jb.dst[base+8] = f2bf_s(w - bfs2f(h));
}

// dst[m] = sum_j src[idx[(rowsel?rowsel[m]:m)*istride + j]]   (wave per row)
__global__ void k_gsum4(const float* __restrict__ src, const int* __restrict__ idx,
                        const int* __restrict__ rowsel, int J, int istride,
                        float* __restrict__ dst, int M){
  int wid = (blockIdx.x<<2) + (threadIdx.x>>6);
  if (wid>=M) return;
  int c = (threadIdx.x&63)<<2;
  int r = rowsel ? rowsel[wid] : wid;
  float4 s = make_float4(0,0,0,0);
  for (int j=0;j<J;j++){
    int id = idx[(size_t)r*istride+j];
    acc4(s, src + (size_t)id*256 + c);
  }
  *(float4*)(dst + (size_t)wid*256 + c) = s;
}

// ---------------------------------------------------------------------------
// MFMA common. Block = 256 thr = 4 waves; wave wc covers cols [wc*64,+64)
// (4 tiles); block covers rows [bid*32,+32) as 2 A-frags.
// ---------------------------------------------------------------------------
__device__ __forceinline__ void build_a(const float* p, bf16x8& hi, bf16x8& lo){
  float4 v0 = *(const float4*)p;
  float4 v1 = *(const float4*)(p+4);
  float vv[8]={v0.x,v0.y,v0.z,v0.w,v1.x,v1.y,v1.z,v1.w};
  #pragma unroll
  for (int j=0;j<8;j++){
    short h = f2bf_s(vv[j]);
    hi[j]=h;
    lo[j]=f2bf_s(vv[j]-bfs2f(h));
  }
}

#define MFMA __builtin_amdgcn_mfma_f32_16x16x32_bf16
#define PRIO_HI __builtin_amdgcn_s_setprio(1)
#define PRIO_LO __builtin_amdgcn_s_setprio(0)

// out = A @ W (bf16x3), f32 out (hnW tables).
__global__ __launch_bounds__(256)
void mfma_mm(const float* __restrict__ A, const short* __restrict__ Bp,
             float* __restrict__ outf, int M)
{
  const int tid=threadIdx.x, lane=tid&63, wc=tid>>6;
  const int rbase = blockIdx.x<<5;
  const int r0 = rbase + (lane&15), r1 = r0 + 16;
  const int koff = (lane>>4)<<3;
  f32x4 zero = {0.f,0.f,0.f,0.f};
  f32x4 acc[2][4];
  #pragma unroll
  for (int rf=0;rf<2;rf++)
    #pragma unroll
    for (int t=0;t<4;t++) acc[rf][t]=zero;

  PRIO_HI;
  for (int kc=0;kc<8;kc++){
    bf16x8 a0h={0,0,0,0,0,0,0,0}, a0l=a0h, a1h=a0h, a1l=a0h;
    if (r0<M) build_a(A + (size_t)r0*256 + kc*32 + koff, a0h, a0l);
    if (r1<M) build_a(A + (size_t)r1*256 + kc*32 + koff, a1h, a1l);
    #pragma unroll
    for (int t=0;t<4;t++){
      const short* p = Bp + (((kc<<4)+(wc<<2)+t)<<10) + (lane<<4);
      bf16x8 bh = *(const bf16x8*)p;
      bf16x8 bl = *(const bf16x8*)(p+8);
      acc[0][t]=MFMA(a0h,bh,acc[0][t],0,0,0);
      acc[1][t]=MFMA(a1h,bh,acc[1][t],0,0,0);
      acc[0][t]=MFMA(a0l,bh,acc[0][t],0,0,0);
      acc[1][t]=MFMA(a1l,bh,acc[1][t],0,0,0);
      acc[0][t]=MFMA(a0h,bl,acc[0][t],0,0,0);
      acc[1][t]=MFMA(a1h,bl,acc[1][t],0,0,0);
    }
  }
  PRIO_LO;
  const int rr = rbase + ((lane>>4)<<2);
  const int cl = lane&15;
  #pragma unroll
  for (int rf=0;rf<2;rf++)
    #pragma unroll
    for (int t=0;t<4;t++){
      int col = (((wc<<2)+t)<<4) + cl;
      #pragma unroll
      for (int r=0;r<4;r++){
        int m = rr + rf*16 + r;
        if (m<M) outf[(size_t)m*256+col] = acc[rf][t][r];
      }
    }
}

// ---------------------------------------------------------------------------
// Projection GEMM: out = relu(A1@B1 [+ A2@B2] + feat(f1)); optional row-0 mask.
// ---------------------------------------------------------------------------
template<int NG>
__global__ __launch_bounds__(256)
void mfma_proj(const float* __restrict__ A1, const int* __restrict__ a1idx, int a1s,
               const float* __restrict__ A2,
               const short* __restrict__ B1p, const short* __restrict__ B2p,
               float* __restrict__ outf, float* __restrict__ outf2,
               Feat f1, int mask0, int M)
{
  const int tid=threadIdx.x, lane=tid&63, wc=tid>>6;
  const int rbase = blockIdx.x<<5;
  const int r0 = rbase + (lane&15), r1 = r0 + 16;
  const int koff = (lane>>4)<<3;
  const float* p0 = (r0<M) ? A1 + (size_t)(a1idx? a1idx[(size_t)r0*a1s] : r0)*256 : nullptr;
  const float* p1 = (r1<M) ? A1 + (size_t)(a1idx? a1idx[(size_t)r1*a1s] : r1)*256 : nullptr;
  f32x4 zero = {0.f,0.f,0.f,0.f};
  f32x4 acc[2][4];
  #pragma unroll
  for (int rf=0;rf<2;rf++)
    #pragma unroll
    for (int t=0;t<4;t++) acc[rf][t]=zero;

  PRIO_HI;
  for (int kc=0;kc<8;kc++){
    bf16x8 a0h={0,0,0,0,0,0,0,0}, a0l=a0h, a1h=a0h, a1l=a0h;
    bf16x8 c0h=a0h, c0l=a0h, c1h=a0h, c1l=a0h;
    if (p0) build_a(p0 + kc*32 + koff, a0h, a0l);
    if (p1) build_a(p1 + kc*32 + koff, a1h, a1l);
    if (NG==2){
      if (r0<M) build_a(A2 + (size_t)r0*256 + kc*32 + koff, c0h, c0l);
      if (r1<M) build_a(A2 + (size_t)r1*256 + kc*32 + koff, c1h, c1l);
    }
    #pragma unroll
    for (int t=0;t<4;t++){
      const short* p = B1p + (((kc<<4)+(wc<<2)+t)<<10) + (lane<<4);
      bf16x8 bh = *(const bf16x8*)p;
      bf16x8 bl = *(const bf16x8*)(p+8);
      acc[0][t]=MFMA(a0h,bh,acc[0][t],0,0,0);
      acc[1][t]=MFMA(a1h,bh,acc[1][t],0,0,0);
      acc[0][t]=MFMA(a0l,bh,acc[0][t],0,0,0);
      acc[1][t]=MFMA(a1l,bh,acc[1][t],0,0,0);
      acc[0][t]=MFMA(a0h,bl,acc[0][t],0,0,0);
      acc[1][t]=MFMA(a1h,bl,acc[1][t],0,0,0);
      if (NG==2){
        const short* q = B2p + (((kc<<4)+(wc<<2)+t)<<10) + (lane<<4);
        bf16x8 dh = *(const bf16x8*)q;
        bf16x8 dl = *(const bf16x8*)(q+8);
        acc[0][t]=MFMA(c0h,dh,acc[0][t],0,0,0);
        acc[1][t]=MFMA(c1h,dh,acc[1][t],0,0,0);
        acc[0][t]=MFMA(c0l,dh,acc[0][t],0,0,0);
        acc[1][t]=MFMA(c1l,dh,acc[1][t],0,0,0);
        acc[0][t]=MFMA(c0h,dl,acc[0][t],0,0,0);
        acc[1][t]=MFMA(c1h,dl,acc[1][t],0,0,0);
      }
    }
  }
  PRIO_LO;
  const int rr = rbase + ((lane>>4)<<2);
  const int cl = lane&15;
  #pragma unroll
  for (int rf=0;rf<2;rf++)
    #pragma unroll
    for (int t=0;t<4;t++){
      int col = (((wc<<2)+t)<<4) + cl;
      #pragma unroll
      for (int r=0;r<4;r++){
        int m = rr + rf*16 + r;
        if (m>=M) continue;
        float v = acc[rf][t][r] + feat_eval(f1, m, col);
        v = fmaxf(v, 0.0f);
        if (mask0 && m==0) v = 0.0f;
        outf[(size_t)m*256+col] = v;
        if (outf2) outf2[(size_t)m*256+col] = v;
      }
    }
}

// ---------------------------------------------------------------------------
// GRU step 1 (h0=0): h = sigmoid(fz)*tanh(fh); write h + bf16 h-tile to LDS;
// then hU = bf16( bf16(h) @ Ur ).
// ---------------------------------------------------------------------------
__global__ __launch_bounds__(256)
void k_step1hu(Feat fz, Feat fh, const short* __restrict__ Bu,
               float* __restrict__ hout, bf16* __restrict__ hUout, int M)
{
  __shared__ short Hs[32][264];
  const int tid=threadIdx.x, lane=tid&63, wc=tid>>6;
  const int rbase = blockIdx.x<<5;
  const int rr = (lane>>4)<<2;
  const int cl = lane&15;
  const int koff = (lane>>4)<<3;

  #pragma unroll
  for (int rf=0;rf<2;rf++)
    #pragma unroll
    for (int t=0;t<4;t++){
      int col = (((wc<<2)+t)<<4) + cl;
      #pragma unroll
      for (int r=0;r<4;r++){
        int lrow = rr + rf*16 + r;
        int m = rbase + lrow;
        float v = 0.f;
        if (m<M && m!=0)
          v = sigm(feat_eval(fz,m,col))*tanh_f(feat_eval(fh,m,col));
        if (m<M) hout[(size_t)m*256+col]=v;
        Hs[lrow][col]=f2bf_s(v);
      }
    }
  __syncthreads();
  const int r0l = lane&15, r1l = r0l+16;
  f32x4 zero = {0.f,0.f,0.f,0.f};
  f32x4 acc[2][4];
  #pragma unroll
  for (int rf=0;rf<2;rf++)
    #pragma unroll
    for (int t=0;t<4;t++) acc[rf][t]=zero;
  PRIO_HI;
  for (int kc=0;kc<8;kc++){
    bf16x8 a0 = *(const bf16x8*)&Hs[r0l][kc*32+koff];
    bf16x8 a1 = *(const bf16x8*)&Hs[r1l][kc*32+koff];
    #pragma unroll
    for (int t=0;t<4;t++){
      const short* p = Bu + (((kc<<4)+(wc<<2)+t)<<10) + (lane<<4);
      bf16x8 bh = *(const bf16x8*)p;
      bf16x8 bl = *(const bf16x8*)(p+8);
      acc[0][t]=MFMA(a0,bh,acc[0][t],0,0,0);
      acc[1][t]=MFMA(a1,bh,acc[1][t],0,0,0);
      acc[0][t]=MFMA(a0,bl,acc[0][t],0,0,0);
      acc[1][t]=MFMA(a1,bl,acc[1][t],0,0,0);
    }
  }
  PRIO_LO;
  #pragma unroll
  for (int rf=0;rf<2;rf++)
    #pragma unroll
    for (int t=0;t<4;t++){
      int col = (((wc<<2)+t)<<4) + cl;
      #pragma unroll
      for (int r=0;r<4;r++){
        int m = rbase + rr + rf*16 + r;
        if (m<M) hUout[(size_t)m*256+col] = __float2bfloat16(acc[rf][t][r]);
      }
    }
}

// ---------------------------------------------------------------------------
// Fused gather + GRU step + next hU.
// ---------------------------------------------------------------------------
template<int GEXT, int DO_HU>
__global__ __launch_bounds__(256)
void mfma_gg(const float* __restrict__ hprev, const bf16* __restrict__ hUprev,
             const int* __restrict__ bgraph, Feat fr,
             const short* __restrict__ Bz, const short* __restrict__ Bh,
             const short* __restrict__ Bze, const short* __restrict__ Bhe,
             const int* __restrict__ aidx, const int* __restrict__ gfm,
             const float* __restrict__ bzb, const float* __restrict__ bhb,
             Feat fz, Feat fh, const short* __restrict__ Bu,
             float* __restrict__ hout, bf16* __restrict__ hUout, int M)
{
  __shared__ float SH[32][260];
  __shared__ short SG[32][264];     // sumgh; reused as bf16 h-tile after barrier
  const int tid=threadIdx.x, lane=tid&63, wc=tid>>6;
  const int rbase = blockIdx.x<<5;
  const int koff = (lane>>4)<<3;

  // ---- Phase A: gather (unroll 2 => ~24 independent loads in flight) ----
  {
    const int c = lane<<2;
    #pragma unroll 2
    for (int s=0;s<8;s++){
      int lrow = (wc<<3) + s;
      int m = rbase + lrow;
      float4 sv = make_float4(0,0,0,0);
      float4 gv = make_float4(0,0,0,0);
      if (m < M){
        float4 fr4 = feat_eval4(fr, m, c);
        const int* bg = bgraph + (size_t)m*6;
        #pragma unroll
        for (int j=0;j<6;j++){
          int id = bg[j];
          float4 h4 = *(const float4*)(hprev + (size_t)id*256 + c);
          uint2  u2 = *(const uint2*)(hUprev + (size_t)id*256 + c);
          float u0=ubf(u2.x&0xffffu), u1=ubf(u2.x>>16);
          float u2f=ubf(u2.y&0xffffu), u3=ubf(u2.y>>16);
          sv.x+=h4.x; sv.y+=h4.y; sv.z+=h4.z; sv.w+=h4.w;
          gv.x += sigm(fr4.x+u0 )*h4.x;
          gv.y += sigm(fr4.y+u1 )*h4.y;
          gv.z += sigm(fr4.z+u2f)*h4.z;
          gv.w += sigm(fr4.w+u3 )*h4.w;
        }
      }
      *(float4*)&SH[lrow][c] = sv;
      uint2 p; p.x = pack2bf(gv.x,gv.y); p.y = pack2bf(gv.z,gv.w);
      *(uint2*)&SG[lrow][c] = p;
    }
  }
  __syncthreads();

  // ---- Phase B: GRU dual GEMM from LDS ----
  const int r0l = lane&15, r1l = r0l+16;
  const int r0 = rbase + r0l, r1 = rbase + r1l;
  f32x4 zero = {0.f,0.f,0.f,0.f};
  f32x4 accz[2][4], acch[2][4];
  #pragma unroll
  for (int rf=0;rf<2;rf++)
    #pragma unroll
    for (int t=0;t<4;t++){ accz[rf][t]=zero; acch[rf][t]=zero; }

  PRIO_HI;
  for (int kc=0;kc<8;kc++){
    bf16x8 a0h, a0l, a1h, a1l;
    build_a(&SH[r0l][kc*32+koff], a0h, a0l);
    build_a(&SH[r1l][kc*32+koff], a1h, a1l);
    bf16x8 s0 = *(const bf16x8*)&SG[r0l][kc*32+koff];
    bf16x8 s1 = *(const bf16x8*)&SG[r1l][kc*32+koff];
    #pragma unroll
    for (int t=0;t<4;t++){
      const short* pz = Bz + (((kc<<4)+(wc<<2)+t)<<10) + (lane<<4);
      const short* ph = Bh + (((kc<<4)+(wc<<2)+t)<<10) + (lane<<4);
      bf16x8 bzh = *(const bf16x8*)pz;
      bf16x8 bzl = *(const bf16x8*)(pz+8);
      bf16x8 bhh = *(const bf16x8*)ph;
      bf16x8 bhl = *(const bf16x8*)(ph+8);
      accz[0][t]=MFMA(a0h,bzh,accz[0][t],0,0,0);
      accz[1][t]=MFMA(a1h,bzh,accz[1][t],0,0,0);
      accz[0][t]=MFMA(a0l,bzh,accz[0][t],0,0,0);
      accz[1][t]=MFMA(a1l,bzh,accz[1][t],0,0,0);
      accz[0][t]=MFMA(a0h,bzl,accz[0][t],0,0,0);
      accz[1][t]=MFMA(a1h,bzl,accz[1][t],0,0,0);
      acch[0][t]=MFMA(s0,bhh,acch[0][t],0,0,0);
      acch[1][t]=MFMA(s1,bhh,acch[1][t],0,0,0);
      acch[0][t]=MFMA(s0,bhl,acch[0][t],0,0,0);
      acch[1][t]=MFMA(s1,bhl,acch[1][t],0,0,0);
    }
  }

  if (GEXT){
    int h0a=-1,h0b=-1,h0c=-1,h1a=-1,h1b=-1,h1c=-1;
    if (r0<M){ h0a=aidx[r0]; h0b=40+gfm[(size_t)r0*4+2]; h0c=44+gfm[(size_t)r0*4+3]; }
    if (r1<M){ h1a=aidx[r1]; h1b=40+gfm[(size_t)r1*4+2]; h1c=44+gfm[(size_t)r1*4+3]; }
    #pragma unroll
    for (int e=0;e<2;e++){
      bf16x8 ax0, ax1;
      #pragma unroll
      for (int j=0;j<8;j++){
        int d = e*32 + koff + j;
        ax0[j] = (d==h0a||d==h0b||d==h0c) ? (short)0x3F80 : (short)0;
        ax1[j] = (d==h1a||d==h1b||d==h1c) ? (short)0x3F80 : (short)0;
      }
      #pragma unroll
      for (int t=0;t<4;t++){
        const short* pe = Bze + (((e<<4)+(wc<<2)+t)<<10) + (lane<<4);
        const short* qe = Bhe + (((e<<4)+(wc<<2)+t)<<10) + (lane<<4);
        bf16x8 bzeh = *(const bf16x8*)pe;
        bf16x8 bzel = *(const bf16x8*)(pe+8);
        bf16x8 bheh = *(const bf16x8*)qe;
        bf16x8 bhel = *(const bf16x8*)(qe+8);
        accz[0][t]=MFMA(ax0,bzeh,accz[0][t],0,0,0);
        accz[1][t]=MFMA(ax1,bzeh,accz[1][t],0,0,0);
        accz[0][t]=MFMA(ax0,bzel,accz[0][t],0,0,0);
        accz[1][t]=MFMA(ax1,bzel,accz[1][t],0,0,0);
        acch[0][t]=MFMA(ax0,bheh,acch[0][t],0,0,0);
        acch[1][t]=MFMA(ax1,bheh,acch[1][t],0,0,0);
        acch[0][t]=MFMA(ax0,bhel,acch[0][t],0,0,0);
        acch[1][t]=MFMA(ax1,bhel,acch[1][t],0,0,0);
      }
    }
  }
  PRIO_LO;

  __syncthreads();   // all SG (sumgh) reads done before epilogue overwrites it

  // ---- Phase C: epilogue (per-row indices hoisted for the i/t path) ----
  const int rr = (lane>>4)<<2;
  const int cl = lane&15;
  int src8[8], pos8[8];
  if (!GEXT){
    #pragma unroll
    for (int rf=0;rf<2;rf++)
      #pragma unroll
      for (int r=0;r<4;r++){
        int m = rbase + rr + rf*16 + r;
        int mm = (m<M)? m : 0;
        src8[rf*4+r] = fz.didx [(size_t)mm*fz.dstride];
        pos8[rf*4+r] = fz.oidx0[(size_t)mm*fz.os0] + fz.oo0;
      }
  }
  #pragma unroll
  for (int rf=0;rf<2;rf++)
    #pragma unroll
    for (int t=0;t<4;t++){
      int col = (((wc<<2)+t)<<4) + cl;
      float fzb=0.f, fhb=0.f;
      if (GEXT){ fzb = bzb[col]; fhb = bhb[col]; }
      #pragma unroll
      for (int r=0;r<4;r++){
        int lrow = rr + rf*16 + r;
        int m = rbase + lrow;
        float v = 0.f;
        if (m<M){
          float fzv, fhv;
          if (GEXT){ fzv = fzb; fhv = fhb; }
          else {
            int i8 = rf*4+r;
            size_t so = (size_t)src8[i8]*256 + col;
            size_t po = (size_t)pos8[i8]*256 + col;
            fzv = fz.bias[col] + fz.dtab[so] + fz.otab[po];
            fhv = fh.bias[col] + fh.dtab[so] + fh.otab[po];
          }
          float z   = sigm  (accz[rf][t][r] + fzv);
          float pre = tanh_f(acch[rf][t][r] + fhv);
          float sh  = SH[lrow][col];
          v = (m==0) ? 0.f : ((1.f-z)*sh + z*pre);
          hout[(size_t)m*256+col] = v;
        }
        if (DO_HU) SG[lrow][col] = f2bf_s(v);
      }
    }

  // ---- Phase D: hU = bf16(h) @ Ur ----
  if (DO_HU){
    __syncthreads();
    f32x4 acc[2][4];
    #pragma unroll
    for (int rf=0;rf<2;rf++)
      #pragma unroll
      for (int t=0;t<4;t++) acc[rf][t]=zero;
    PRIO_HI;
    for (int kc=0;kc<8;kc++){
      bf16x8 a0 = *(const bf16x8*)&SG[r0l][kc*32+koff];
      bf16x8 a1 = *(const bf16x8*)&SG[r1l][kc*32+koff];
      #pragma unroll
      for (int t=0;t<4;t++){
        const short* p = Bu + (((kc<<4)+(wc<<2)+t)<<10) + (lane<<4);
        bf16x8 bh = *(const bf16x8*)p;
        bf16x8 bl = *(const bf16x8*)(p+8);
        acc[0][t]=MFMA(a0,bh,acc[0][t],0,0,0);
        acc[1][t]=MFMA(a1,bh,acc[1][t],0,0,0);
        acc[0][t]=MFMA(a0,bl,acc[0][t],0,0,0);
        acc[1][t]=MFMA(a1,bl,acc[1][t],0,0,0);
      }
    }
    PRIO_LO;
    #pragma unroll
    for (int rf=0;rf<2;rf++)
      #pragma unroll
      for (int t=0;t<4;t++){
        int col = (((wc<<2)+t)<<4) + cl;
        #pragma unroll
        for (int r=0;r<4;r++){
          int m = rbase + rr + rf*16 + r;
          if (m<M) hUout[(size_t)m*256+col] = __float2bfloat16(acc[rf][t][r]);
        }
      }
  }
}

// ---------------------------------------------------------------------------
// Vector GEMM kept only for the tiny Wroot (M=256, tanh epilogue).
// ---------------------------------------------------------------------------
template<int NG, int MODE>
__global__ __launch_bounds__(256)
void gemm256(const float* __restrict__ A1, const float* __restrict__ B1,
             const float* __restrict__ A2, const float* __restrict__ B2,
             float* __restrict__ Cf, int M, Feat f1, int mask0)
{
  __shared__ float As[NG][16][36];
  __shared__ float Bs[NG][16][260];
  const int tid = threadIdx.x;
  const int bm = blockIdx.x<<5;
  const int tm = (tid>>5)<<2;
  const int c0 = (tid&31)<<2;

  float acc[NG][4][8];
  #pragma unroll
  for (int g=0;g<NG;g++)
    #pragma unroll
    for (int i=0;i<4;i++)
      #pragma unroll
      for (int j=0;j<8;j++) acc[g][i][j]=0.f;

  const int t7  = tid & 127;
  const int alm = t7>>2;
  const int alk = (t7&3)<<2;
  const int arow = bm + alm;
  const int amat = (NG==2)? (tid>>7) : 0;
  const bool astage = (NG==2) || (tid<128);

  for (int k0=0;k0<256;k0+=16){
    float a0=0,a1=0,a2=0,a3=0;
    if (astage && arow<M){
      const float* src = (amat==0)? A1 : A2;
      float4 v = *(const float4*)(src + (size_t)arow*256 + k0 + alk);
      a0=v.x; a1=v.y; a2=v.z; a3=v.w;
    }
    float4 breg[NG][4];
    #pragma unroll
    for (int g=0; g<NG; g++){
      const float* B = (g==0)? B1 : B2;
      #pragma unroll
      for (int j=0;j<4;j++){
        int slot = tid + 256*j;
        int kb = slot>>6, nb = (slot&63)<<2;
        breg[g][j] = *(const float4*)(B + (size_t)(k0+kb)*256 + nb);
      }
    }
    __syncthreads();
    if (astage){
      As[amat][alk+0][alm]=a0; As[amat][alk+1][alm]=a1;
      As[amat][alk+2][alm]=a2; As[amat][alk+3][alm]=a3;
    }
    #pragma unroll
    for (int g=0; g<NG; g++){
      #pragma unroll
      for (int j=0;j<4;j++){
        int slot = tid + 256*j;
        int kb = slot>>6, nb = (slot&63)<<2;
        *(float4*)&Bs[g][kb][nb] = breg[g][j];
      }
    }
    __syncthreads();
    #pragma unroll
    for (int k=0;k<16;k++){
      #pragma unroll
      for (int g=0;g<NG;g++){
        float4 av = *(const float4*)&As[g][k][tm];
        float4 b0 = *(const float4*)&Bs[g][k][c0];
        float4 b1 = *(const float4*)&Bs[g][k][c0+128];
        float a_[4]={av.x,av.y,av.z,av.w};
        float b_[8]={b0.x,b0.y,b0.z,b0.w,b1.x,b1.y,b1.z,b1.w};
        #pragma unroll
        for (int i=0;i<4;i++)
          #pragma unroll
          for (int j=0;j<8;j++)
            acc[g][i][j] = fmaf(a_[i], b_[j], acc[g][i][j]);
      }
    }
  }

  #pragma unroll
  for (int i=0;i<4;i++){
    int m = bm + tm + i;
    if (m >= M) continue;
    #pragma unroll
    for (int half=0; half<2; half++){
      int c = c0 + half*128;
      float4 r;
      float* rr = &r.x;
      float4 ft = feat_eval4(f1, m, c);
      float fv[4]={ft.x,ft.y,ft.z,ft.w};
      #pragma unroll
      for (int j=0;j<4;j++){
        float s = acc[0][i][half*4+j] + (NG>1?acc[1][i][half*4+j]:0.f) + fv[j];
        float v = (MODE==1)? fmaxf(s,0.f) : tanhf(s);
        if (MODE==1 && mask0 && m==0) v = 0.f;
        rr[j] = v;
      }
      *(float4*)(Cf + (size_t)m*256+c) = r;
    }
  }
}

// ---------------------------------------------------------------------------
extern "C" void kernel_launch(void* const* d_in, const int* in_sizes, int n_in,
                              void* d_out, int out_size, void* d_ws, size_t ws_size,
                              hipStream_t stream)
{
  const int* t_fnode  = (const int*)d_in[0];
  const int* t_fmess  = (const int*)d_in[1];
  const int* t_agraph = (const int*)d_in[2];
  const int* t_bgraph = (const int*)d_in[3];
  const int* t_cgraph = (const int*)d_in[4];
  const int* g_fnode  = (const int*)d_in[5];
  const int* g_fmess  = (const int*)d_in[6];
  const int* g_agraph = (const int*)d_in[7];
  const int* g_bgraph = (const int*)d_in[8];
  const int* roots    = (const int*)d_in[9];
  const float* E_c     = (const float*)d_in[10];
  const float* E_i     = (const float*)d_in[11];
  const float* Wc_w    = (const float*)d_in[12];
  const float* Wc_b    = (const float*)d_in[13];
  const float* Wi_w    = (const float*)d_in[14];
  const float* Wi_b    = (const float*)d_in[15];
  const float* Wroot_w = (const float*)d_in[16];
  const float* Wroot_b = (const float*)d_in[17];
  const float* t_Wo_w  = (const float*)d_in[18];
  const float* t_Wo_b  = (const float*)d_in[19];
  const float* t_Wz_w  = (const float*)d_in[20];
  const float* t_Wz_b  = (const float*)d_in[21];
  const float* t_Wr_w  = (const float*)d_in[22];
  const float* t_Ur_w  = (const float*)d_in[23];
  const float* t_Ur_b  = (const float*)d_in[24];
  const float* t_Wh_w  = (const float*)d_in[25];
  const float* t_Wh_b  = (const float*)d_in[26];
  const float* i_Wo_w  = (const float*)d_in[27];
  const float* i_Wo_b  = (const float*)d_in[28];
  const float* i_Wz_w  = (const float*)d_in[29];
  const float* i_Wz_b  = (const float*)d_in[30];
  const float* i_Wr_w  = (const float*)d_in[31];
  const float* i_Ur_w  = (const float*)d_in[32];
  const float* i_Ur_b  = (const float*)d_in[33];
  const float* i_Wh_w  = (const float*)d_in[34];
  const float* i_Wh_b  = (const float*)d_in[35];
  const float* g_Wo_w  = (const float*)d_in[36];
  const float* g_Wo_b  = (const float*)d_in[37];
  const float* g_Wz_w  = (const float*)d_in[38];
  const float* g_Wz_b  = (const float*)d_in[39];
  const float* g_Wr_w  = (const float*)d_in[40];
  const float* g_Ur_w  = (const float*)d_in[41];
  const float* g_Ur_b  = (const float*)d_in[42];
  const float* g_Wh_w  = (const float*)d_in[43];
  const float* g_Wh_b  = (const float*)d_in[44];

  float* out        = (float*)d_out;
  float* out_hroot  = out;
  float* out_htree  = out + (size_t)65536;
  float* out_hinter = out + (size_t)65536 + 2048000;
  float* out_hatom  = out + (size_t)65536 + 2048000 + 2048000;

  // ---- workspace (~162.3 MB) ------------------------------------------------
  char* base = (char*)d_ws;
  int*   aidx   = (int*)base;                              // 262144 B reserved
  short* SP     = (short*)(base + 262144);                 // plane region (8 MB)
  float* hbuf   = (float*)(base + 262144 + 8388608);       // h_a   50000x256 f32
  float* hbufB  = hbuf + (size_t)12800000;                 // h_b   50000x256 f32
  bf16*  hUbuf  = (bf16*)(hbufB + (size_t)12800000);       // hU_a  50000x256 bf16
  bf16*  hUbufB = hUbuf + (size_t)12800000;                // hU_b  50000x256 bf16

  auto GP = [&](int i)->short* { return SP + (size_t)i*131072; };
  short* EZ = SP + (size_t)9*131072;
  short* EH = EZ + 32768;
  auto HP = [&](int j)->short* { return EH + 32768 + (size_t)j*131072; };
  short* P2 = EH + 32768 + (size_t)6*131072;
  auto PP = [&](int j)->short* { return P2 + (size_t)j*131072; };

  float* neibG    = hbufB;
  float* hatom    = hbufB + (size_t)25000*256;
  float* neib_t   = hbuf;
  float* hn_i     = hbuf  + (size_t)16000*256;
  float* hnWz     = hbufB + (size_t)16000*256;
  float* hnWr     = hbufB + (size_t)24000*256;
  float* hnWh     = hbufB + (size_t)32000*256;
  float* nei_i    = hbufB;
  float* hinter   = hbufB + (size_t)8000*256;
  float* hn_t     = hbuf  + (size_t)32000*256;
  float* nei_t    = hbufB;
  float* hn_roots = hbufB + (size_t)8000*256;
  float* nei_root = hbufB + (size_t)8256*256;

  (void)in_sizes; (void)n_in; (void)out_size; (void)ws_size;

  // ---- weight split/swizzle: one batched launch ----------------------------
  SJobs js;
  js.j[0]  = { g_Ur_w,                    GP(0), 256, 0 };
  js.j[1]  = { g_Wz_w + (size_t)64*256,   GP(1), 256, 0 };
  js.j[2]  = { g_Wh_w + (size_t)64*256,   GP(2), 256, 0 };
  js.j[3]  = { i_Ur_w,                    GP(3), 256, 0 };
  js.j[4]  = { i_Wz_w + (size_t)276*256,  GP(4), 256, 0 };
  js.j[5]  = { i_Wh_w + (size_t)276*256,  GP(5), 256, 0 };
  js.j[6]  = { t_Ur_w,                    GP(6), 256, 0 };
  js.j[7]  = { t_Wz_w + (size_t)276*256,  GP(7), 256, 0 };
  js.j[8]  = { t_Wh_w + (size_t)276*256,  GP(8), 256, 0 };
  js.j[9]  = { g_Wz_w,                    EZ,     64, 0 };
  js.j[10] = { g_Wh_w,                    EH,     64, 0 };
  js.j[11] = { i_Wz_w,                    HP(0), 256, 0 };
  js.j[12] = { i_Wr_w,                    HP(1), 256, 0 };
  js.j[13] = { i_Wh_w,                    HP(2), 256, 0 };
  js.j[14] = { t_Wz_w,                    HP(3), 256, 0 };
  js.j[15] = { t_Wr_w,                    HP(4), 256, 0 };
  js.j[16] = { t_Wh_w,                    HP(5), 256, 0 };
  js.j[17] = { Wi_w,                      PP(0), 256, 0 };
  js.j[18] = { Wi_w + (size_t)256*256,    PP(1), 256, 0 };
  js.j[19] = { Wc_w,                      PP(2), 256, 0 };
  js.j[20] = { Wc_w + (size_t)256*256,    PP(3), 256, 0 };
  js.j[21] = { i_Wo_w,                    PP(4), 256, 0 };
  js.j[22] = { i_Wo_w + (size_t)256*256,  PP(5), 256, 0 };
  js.j[23] = { t_Wo_w,                    PP(6), 256, 0 };
  js.j[24] = { t_Wo_w + (size_t)256*256,  PP(7), 256, 0 };
  js.j[25] = { g_Wo_w + (size_t)40*256,   PP(8), 256, 0 };
  k_splitw_b<<<dim3(256,26),256,0,stream>>>(js);

  // ---- feature descriptors -------------------------------------------------
  Feat fzg{}; fzg.otab=g_Wz_w; fzg.oidx0=aidx;      fzg.os0=1; fzg.oo0=0;
              fzg.oidx1=g_fmess+2; fzg.os1=4; fzg.oo1=40;
              fzg.oidx2=g_fmess+3; fzg.os2=4; fzg.oo2=44; fzg.bias=g_Wz_b;
  Feat frg = fzg; frg.otab=g_Wr_w; frg.bias=g_Ur_b;
  Feat fhg = fzg; fhg.otab=g_Wh_w; fhg.bias=g_Wh_b;

  Feat fzi{}; fzi.dtab=hnWz; fzi.didx=t_fmess; fzi.dstride=3;
              fzi.otab=i_Wz_w; fzi.oidx0=t_fmess+2; fzi.os0=3; fzi.oo0=256; fzi.bias=i_Wz_b;
  Feat fri = fzi; fri.dtab=hnWr; fri.otab=i_Wr_w; fri.bias=i_Ur_b;
  Feat fhi = fzi; fhi.dtab=hnWh; fhi.otab=i_Wh_w; fhi.bias=i_Wh_b;

  Feat fzt = fzi; fzt.otab=t_Wz_w; fzt.bias=t_Wz_b;
  Feat frt = fri; frt.otab=t_Wr_w; frt.bias=t_Ur_b;
  Feat fht = fhi; fht.otab=t_Wh_w; fht.bias=t_Wh_b;

  Feat fnone{};

  // ---- GRU driver: step1+hU, then 4 x fused(gather+GRU+hU), ping-pong ------
  auto run_gru = [&](int M, const int* bgraph, int p, bool gext,
                     Feat fz, Feat fr, Feat fh)->float* {
    int gb32 = (M+31)/32;
    const short* Bu = GP(p*3+0);
    const short* Bz = GP(p*3+1);
    const short* Bh = GP(p*3+2);
    k_step1hu<<<gb32,256,0,stream>>>(fz, fh, Bu, hbuf, hUbuf, M);
    float* hA = hbuf;  bf16* uA = hUbuf;
    float* hB = hbufB; bf16* uB = hUbufB;
    for (int d=0; d<4; ++d){
      if (d<3){
        if (gext)
          mfma_gg<1,1><<<gb32,256,0,stream>>>(hA, uA, bgraph, fr, Bz, Bh,
              EZ, EH, aidx, g_fmess, g_Wz_b, g_Wh_b, fnone, fnone, Bu, hB, uB, M);
        else
          mfma_gg<0,1><<<gb32,256,0,stream>>>(hA, uA, bgraph, fr, Bz, Bh,
              nullptr,nullptr,nullptr,nullptr,nullptr,nullptr, fz, fh, Bu, hB, uB, M);
      } else {
        if (gext)
          mfma_gg<1,0><<<gb32,256,0,stream>>>(hA, uA, bgraph, fr, Bz, Bh,
              EZ, EH, aidx, g_fmess, g_Wz_b, g_Wh_b, fnone, fnone, nullptr, hB, nullptr, M);
        else
          mfma_gg<0,0><<<gb32,256,0,stream>>>(hA, uA, bgraph, fr, Bz, Bh,
              nullptr,nullptr,nullptr,nullptr,nullptr,nullptr, fz, fh, nullptr, hB, nullptr, M);
      }
      float* th=hA; hA=hB; hB=th;
      bf16*  tu=uA; uA=uB; uB=tu;
    }
    return hA;   // 4 swaps -> hbuf
  };

  // ==== Phase G: atom graph MPN ============================================
  k_aidx<<<(MA_+255)/256,256,0,stream>>>(g_fnode, g_fmess, aidx, MA_);
  float* hg = run_gru(MA_, g_bgraph, 0, true, fzg, frg, fhg);
  k_gsum4<<<(NA_+3)/4,256,0,stream>>>(hg, g_agraph, nullptr, 6, 6, neibG, NA_);
  Feat fWo{}; fWo.otab=g_Wo_w; fWo.oidx0=g_fnode; fWo.os0=1; fWo.oo0=0; fWo.bias=g_Wo_b;
  mfma_proj<1><<<(NA_+31)/32,256,0,stream>>>(neibG, nullptr, 1, nullptr,
      PP(8), nullptr, hatom, out_hatom, fWo, 1, NA_);

  // ==== Phase I prep ========================================================
  k_gsum4<<<(NT_+3)/4,256,0,stream>>>(hatom, t_cgraph, nullptr, 12, 12, neib_t, NT_);
  Feat fbWi{}; fbWi.bias=Wi_b;
  mfma_proj<2><<<NT_/32,256,0,stream>>>(E_i, t_fnode+1, 2, neib_t,
      PP(0), PP(1), hn_i, nullptr, fbWi, 0, NT_);
  mfma_mm<<<NT_/32,256,0,stream>>>(hn_i, HP(0), hnWz, NT_);
  mfma_mm<<<NT_/32,256,0,stream>>>(hn_i, HP(1), hnWr, NT_);
  mfma_mm<<<NT_/32,256,0,stream>>>(hn_i, HP(2), hnWh, NT_);

  // ==== Phase I GRU =========================================================
  float* hi = run_gru(MT_, t_bgraph, 1, false, fzi, fri, fhi);
  k_gsum4<<<(NT_+3)/4,256,0,stream>>>(hi, t_agraph, nullptr, 6, 6, nei_i, NT_);
  Feat fbWoi{}; fbWoi.bias=i_Wo_b;
  mfma_proj<2><<<NT_/32,256,0,stream>>>(hn_i, nullptr, 1, nei_i,
      PP(4), PP(5), hinter, out_hinter, fbWoi, 1, NT_);

  // ==== Phase T prep ========================================================
  Feat fbWc{}; fbWc.bias=Wc_b;
  mfma_proj<2><<<NT_/32,256,0,stream>>>(E_c, t_fnode, 2, hinter,
      PP(2), PP(3), hn_t, nullptr, fbWc, 0, NT_);
  mfma_mm<<<NT_/32,256,0,stream>>>(hn_t, HP(3), hnWz, NT_);
  mfma_mm<<<NT_/32,256,0,stream>>>(hn_t, HP(4), hnWr, NT_);
  mfma_mm<<<NT_/32,256,0,stream>>>(hn_t, HP(5), hnWh, NT_);

  // ==== Phase T GRU =========================================================
  float* ht = run_gru(MT_, t_bgraph, 2, false, fzt, frt, fht);
  k_gsum4<<<(NT_+3)/4,256,0,stream>>>(ht, t_agraph, nullptr, 6, 6, nei_t, NT_);
  Feat fbWot{}; fbWot.bias=t_Wo_b;
  mfma_proj<2><<<NT_/32,256,0,stream>>>(hn_t, nullptr, 1, nei_t,
      PP(6), PP(7), out_htree, nullptr, fbWot, 1, NT_);

  // ==== Root ================================================================
  k_gsum4<<<(NROOT_+3)/4,256,0,stream>>>(hn_t, roots, nullptr, 1, 1, hn_roots, NROOT_);
  k_gsum4<<<(NROOT_+3)/4,256,0,stream>>>(ht, t_agraph, roots, 6, 6, nei_root, NROOT_);
  Feat fbWr{}; fbWr.bias=Wroot_b;
  gemm256<2,2><<<NROOT_/32,256,0,stream>>>(hn_roots, Wroot_w, nei_root,
      Wroot_w + (size_t)256*256, out_hroot, NROOT_, fbWr, 0);
}

// Round 15
// 1814.058 us; speedup vs baseline: 1.0246x; 1.0246x over previous
//
#include <hip/hip_runtime.h>
#include <hip/hip_bf16.h>
#include <hip/hip_fp16.h>
#include <math.h>

typedef __hip_bfloat16 bf16;
typedef __attribute__((ext_vector_type(8))) short  bf16x8;
typedef __attribute__((ext_vector_type(4))) float  f32x4;

#define NT_ 8000
#define MT_ 16000
#define NA_ 25000
#define MA_ 50000
#define NROOT_ 256

// ---------------------------------------------------------------------------
struct Feat {
  const float* dtab; const int* didx; int dstride;
  const float* otab;
  const int* oidx0; int os0; int oo0;
  const int* oidx1; int os1; int oo1;
  const int* oidx2; int os2; int oo2;
  const float* bias;
};

// Fast HW-native transcendentals (v_exp_f32 + v_rcp_f32; rel err ~1e-6).
__device__ __forceinline__ float rcpf_(float x){ return __builtin_amdgcn_rcpf(x); }
__device__ __forceinline__ float sigm(float x){ return rcpf_(1.0f + __expf(-x)); }
__device__ __forceinline__ float tanh_f(float x){
  float t = __expf(2.0f*x);
  return 1.0f - 2.0f*rcpf_(t + 1.0f);
}

__device__ __forceinline__ float ubf(unsigned int u){ union{unsigned int i; float f;} x; x.i = u<<16; return x.f; }
__device__ __forceinline__ unsigned int pack2bf(float a, float b){
  bf16 x = __float2bfloat16(a), y = __float2bfloat16(b);
  unsigned short ux = *(unsigned short*)&x, uy = *(unsigned short*)&y;
  return (unsigned int)ux | ((unsigned int)uy<<16);
}
__device__ __forceinline__ short f2bf_s(float f){
  bf16 b = __float2bfloat16(f);
  return *(short*)&b;
}
__device__ __forceinline__ float bfs2f(short s){ return ubf((unsigned short)s); }

__device__ __forceinline__ void acc4(float4& v, const float* p){
  float4 t = *(const float4*)p;
  v.x+=t.x; v.y+=t.y; v.z+=t.z; v.w+=t.w;
}
__device__ __forceinline__ float4 feat_eval4(const Feat& f, int m, int n){
  float4 v = make_float4(0,0,0,0);
  if (f.bias) acc4(v, f.bias + n);
  if (f.dtab) acc4(v, f.dtab + (size_t)f.didx[(size_t)m*f.dstride]*256 + n);
  if (f.otab){
    acc4(v, f.otab + (size_t)(f.oidx0[(size_t)m*f.os0]+f.oo0)*256 + n);
    if (f.oidx1) acc4(v, f.otab + (size_t)(f.oidx1[(size_t)m*f.os1]+f.oo1)*256 + n);
    if (f.oidx2) acc4(v, f.otab + (size_t)(f.oidx2[(size_t)m*f.os2]+f.oo2)*256 + n);
  }
  return v;
}
__device__ __forceinline__ float feat_eval(const Feat& f, int m, int n){
  float v = 0.0f;
  if (f.bias) v += f.bias[n];
  if (f.dtab) v += f.dtab[(size_t)f.didx[(size_t)m*f.dstride]*256 + n];
  if (f.otab){
    v += f.otab[((size_t)(f.oidx0[(size_t)m*f.os0]+f.oo0))*256 + n];
    if (f.oidx1) v += f.otab[((size_t)(f.oidx1[(size_t)m*f.os1]+f.oo1))*256 + n];
    if (f.oidx2) v += f.otab[((size_t)(f.oidx2[(size_t)m*f.os2]+f.oo2))*256 + n];
  }
  return v;
}

// ---------------------------------------------------------------------------
__global__ void k_aidx(const int* __restrict__ g_fnode, const int* __restrict__ g_fmess,
                       int* __restrict__ aidx, int M){
  int m = blockIdx.x*blockDim.x + threadIdx.x;
  if (m<M) aidx[m] = g_fnode[g_fmess[(size_t)m*4]];
}

// Batched weight split/swizzle.
struct SJob { const float* src; short* dst; int nrow; int pad; };
struct SJobs { SJob j[26]; };
__global__ void k_splitw_b(SJobs js){
  SJob jb = js.j[blockIdx.y];
  int idx = blockIdx.x*256 + threadIdx.x;
  if (idx >= jb.nrow*256) return;
  int k = idx>>8, n = idx&255;
  float w = jb.src[idx];
  int base = (((k>>5)*16 + (n>>4))<<10) + (((n&15) + (((k>>3)&3)<<4))<<4) + (k&7);
  short h = f2bf_s(w);
  jb.dst[base]   = h;
  jb.dst[base+8] = f2bf_s(w - bfs2f(h));
}

// dst[m] = sum_j src[idx[(rowsel?rowsel[m]:m)*istride + j]]   (wave per row)
__global__ void k_gsum4(const float* __restrict__ src, const int* __restrict__ idx,
                        const int* __restrict__ rowsel, int J, int istride,
                        float* __restrict__ dst, int M){
  int wid = (blockIdx.x<<2) + (threadIdx.x>>6);
  if (wid>=M) return;
  int c = (threadIdx.x&63)<<2;
  int r = rowsel ? rowsel[wid] : wid;
  float4 s = make_float4(0,0,0,0);
  for (int j=0;j<J;j++){
    int id = idx[(size_t)r*istride+j];
    acc4(s, src + (size_t)id*256 + c);
  }
  *(float4*)(dst + (size_t)wid*256 + c) = s;
}

// ---------------------------------------------------------------------------
// MFMA common. Block = 256 thr = 4 waves; wave wc covers cols [wc*64,+64)
// (4 tiles); block covers rows [bid*32,+32) as 2 A-frags.
// ---------------------------------------------------------------------------
__device__ __forceinline__ void build_a(const float* p, bf16x8& hi, bf16x8& lo){
  float4 v0 = *(const float4*)p;
  float4 v1 = *(const float4*)(p+4);
  float vv[8]={v0.x,v0.y,v0.z,v0.w,v1.x,v1.y,v1.z,v1.w};
  #pragma unroll
  for (int j=0;j<8;j++){
    short h = f2bf_s(vv[j]);
    hi[j]=h;
    lo[j]=f2bf_s(vv[j]-bfs2f(h));
  }
}

#define MFMA __builtin_amdgcn_mfma_f32_16x16x32_bf16
#define PRIO_HI __builtin_amdgcn_s_setprio(1)
#define PRIO_LO __builtin_amdgcn_s_setprio(0)

// out = A @ W (bf16x3), f32 out (hnW tables).
__global__ __launch_bounds__(256)
void mfma_mm(const float* __restrict__ A, const short* __restrict__ Bp,
             float* __restrict__ outf, int M)
{
  const int tid=threadIdx.x, lane=tid&63, wc=tid>>6;
  const int rbase = blockIdx.x<<5;
  const int r0 = rbase + (lane&15), r1 = r0 + 16;
  const int koff = (lane>>4)<<3;
  f32x4 zero = {0.f,0.f,0.f,0.f};
  f32x4 acc[2][4];
  #pragma unroll
  for (int rf=0;rf<2;rf++)
    #pragma unroll
    for (int t=0;t<4;t++) acc[rf][t]=zero;

  PRIO_HI;
  for (int kc=0;kc<8;kc++){
    bf16x8 a0h={0,0,0,0,0,0,0,0}, a0l=a0h, a1h=a0h, a1l=a0h;
    if (r0<M) build_a(A + (size_t)r0*256 + kc*32 + koff, a0h, a0l);
    if (r1<M) build_a(A + (size_t)r1*256 + kc*32 + koff, a1h, a1l);
    #pragma unroll
    for (int t=0;t<4;t++){
      const short* p = Bp + (((kc<<4)+(wc<<2)+t)<<10) + (lane<<4);
      bf16x8 bh = *(const bf16x8*)p;
      bf16x8 bl = *(const bf16x8*)(p+8);
      acc[0][t]=MFMA(a0h,bh,acc[0][t],0,0,0);
      acc[1][t]=MFMA(a1h,bh,acc[1][t],0,0,0);
      acc[0][t]=MFMA(a0l,bh,acc[0][t],0,0,0);
      acc[1][t]=MFMA(a1l,bh,acc[1][t],0,0,0);
      acc[0][t]=MFMA(a0h,bl,acc[0][t],0,0,0);
      acc[1][t]=MFMA(a1h,bl,acc[1][t],0,0,0);
    }
  }
  PRIO_LO;
  const int rr = rbase + ((lane>>4)<<2);
  const int cl = lane&15;
  #pragma unroll
  for (int rf=0;rf<2;rf++)
    #pragma unroll
    for (int t=0;t<4;t++){
      int col = (((wc<<2)+t)<<4) + cl;
      #pragma unroll
      for (int r=0;r<4;r++){
        int m = rr + rf*16 + r;
        if (m<M) outf[(size_t)m*256+col] = acc[rf][t][r];
      }
    }
}

// ---------------------------------------------------------------------------
// Projection GEMM: out = relu(A1@B1 [+ A2@B2] + feat(f1)); optional row-0 mask.
// ---------------------------------------------------------------------------
template<int NG>
__global__ __launch_bounds__(256)
void mfma_proj(const float* __restrict__ A1, const int* __restrict__ a1idx, int a1s,
               const float* __restrict__ A2,
               const short* __restrict__ B1p, const short* __restrict__ B2p,
               float* __restrict__ outf, float* __restrict__ outf2,
               Feat f1, int mask0, int M)
{
  const int tid=threadIdx.x, lane=tid&63, wc=tid>>6;
  const int rbase = blockIdx.x<<5;
  const int r0 = rbase + (lane&15), r1 = r0 + 16;
  const int koff = (lane>>4)<<3;
  const float* p0 = (r0<M) ? A1 + (size_t)(a1idx? a1idx[(size_t)r0*a1s] : r0)*256 : nullptr;
  const float* p1 = (r1<M) ? A1 + (size_t)(a1idx? a1idx[(size_t)r1*a1s] : r1)*256 : nullptr;
  f32x4 zero = {0.f,0.f,0.f,0.f};
  f32x4 acc[2][4];
  #pragma unroll
  for (int rf=0;rf<2;rf++)
    #pragma unroll
    for (int t=0;t<4;t++) acc[rf][t]=zero;

  PRIO_HI;
  for (int kc=0;kc<8;kc++){
    bf16x8 a0h={0,0,0,0,0,0,0,0}, a0l=a0h, a1h=a0h, a1l=a0h;
    bf16x8 c0h=a0h, c0l=a0h, c1h=a0h, c1l=a0h;
    if (p0) build_a(p0 + kc*32 + koff, a0h, a0l);
    if (p1) build_a(p1 + kc*32 + koff, a1h, a1l);
    if (NG==2){
      if (r0<M) build_a(A2 + (size_t)r0*256 + kc*32 + koff, c0h, c0l);
      if (r1<M) build_a(A2 + (size_t)r1*256 + kc*32 + koff, c1h, c1l);
    }
    #pragma unroll
    for (int t=0;t<4;t++){
      const short* p = B1p + (((kc<<4)+(wc<<2)+t)<<10) + (lane<<4);
      bf16x8 bh = *(const bf16x8*)p;
      bf16x8 bl = *(const bf16x8*)(p+8);
      acc[0][t]=MFMA(a0h,bh,acc[0][t],0,0,0);
      acc[1][t]=MFMA(a1h,bh,acc[1][t],0,0,0);
      acc[0][t]=MFMA(a0l,bh,acc[0][t],0,0,0);
      acc[1][t]=MFMA(a1l,bh,acc[1][t],0,0,0);
      acc[0][t]=MFMA(a0h,bl,acc[0][t],0,0,0);
      acc[1][t]=MFMA(a1h,bl,acc[1][t],0,0,0);
      if (NG==2){
        const short* q = B2p + (((kc<<4)+(wc<<2)+t)<<10) + (lane<<4);
        bf16x8 dh = *(const bf16x8*)q;
        bf16x8 dl = *(const bf16x8*)(q+8);
        acc[0][t]=MFMA(c0h,dh,acc[0][t],0,0,0);
        acc[1][t]=MFMA(c1h,dh,acc[1][t],0,0,0);
        acc[0][t]=MFMA(c0l,dh,acc[0][t],0,0,0);
        acc[1][t]=MFMA(c1l,dh,acc[1][t],0,0,0);
        acc[0][t]=MFMA(c0h,dl,acc[0][t],0,0,0);
        acc[1][t]=MFMA(c1h,dl,acc[1][t],0,0,0);
      }
    }
  }
  PRIO_LO;
  const int rr = rbase + ((lane>>4)<<2);
  const int cl = lane&15;
  #pragma unroll
  for (int rf=0;rf<2;rf++)
    #pragma unroll
    for (int t=0;t<4;t++){
      int col = (((wc<<2)+t)<<4) + cl;
      #pragma unroll
      for (int r=0;r<4;r++){
        int m = rr + rf*16 + r;
        if (m>=M) continue;
        float v = acc[rf][t][r] + feat_eval(f1, m, col);
        v = fmaxf(v, 0.0f);
        if (mask0 && m==0) v = 0.0f;
        outf[(size_t)m*256+col] = v;
        if (outf2) outf2[(size_t)m*256+col] = v;
      }
    }
}

// ---------------------------------------------------------------------------
// GRU step 1 (h0=0): h = sigmoid(fz)*tanh(fh); write h (fp16) + bf16 LDS tile;
// then hU = bf16( bf16(h) @ Ur ).
// ---------------------------------------------------------------------------
__global__ __launch_bounds__(256)
void k_step1hu(Feat fz, Feat fh, const short* __restrict__ Bu,
               __half* __restrict__ houtH, bf16* __restrict__ hUout, int M)
{
  __shared__ short Hs[32][264];
  const int tid=threadIdx.x, lane=tid&63, wc=tid>>6;
  const int rbase = blockIdx.x<<5;
  const int rr = (lane>>4)<<2;
  const int cl = lane&15;
  const int koff = (lane>>4)<<3;

  #pragma unroll
  for (int rf=0;rf<2;rf++)
    #pragma unroll
    for (int t=0;t<4;t++){
      int col = (((wc<<2)+t)<<4) + cl;
      #pragma unroll
      for (int r=0;r<4;r++){
        int lrow = rr + rf*16 + r;
        int m = rbase + lrow;
        float v = 0.f;
        if (m<M && m!=0)
          v = sigm(feat_eval(fz,m,col))*tanh_f(feat_eval(fh,m,col));
        if (m<M) houtH[(size_t)m*256+col]=__float2half(v);
        Hs[lrow][col]=f2bf_s(v);
      }
    }
  __syncthreads();
  const int r0l = lane&15, r1l = r0l+16;
  f32x4 zero = {0.f,0.f,0.f,0.f};
  f32x4 acc[2][4];
  #pragma unroll
  for (int rf=0;rf<2;rf++)
    #pragma unroll
    for (int t=0;t<4;t++) acc[rf][t]=zero;
  PRIO_HI;
  for (int kc=0;kc<8;kc++){
    bf16x8 a0 = *(const bf16x8*)&Hs[r0l][kc*32+koff];
    bf16x8 a1 = *(const bf16x8*)&Hs[r1l][kc*32+koff];
    #pragma unroll
    for (int t=0;t<4;t++){
      const short* p = Bu + (((kc<<4)+(wc<<2)+t)<<10) + (lane<<4);
      bf16x8 bh = *(const bf16x8*)p;
      bf16x8 bl = *(const bf16x8*)(p+8);
      acc[0][t]=MFMA(a0,bh,acc[0][t],0,0,0);
      acc[1][t]=MFMA(a1,bh,acc[1][t],0,0,0);
      acc[0][t]=MFMA(a0,bl,acc[0][t],0,0,0);
      acc[1][t]=MFMA(a1,bl,acc[1][t],0,0,0);
    }
  }
  PRIO_LO;
  #pragma unroll
  for (int rf=0;rf<2;rf++)
    #pragma unroll
    for (int t=0;t<4;t++){
      int col = (((wc<<2)+t)<<4) + cl;
      #pragma unroll
      for (int r=0;r<4;r++){
        int m = rbase + rr + rf*16 + r;
        if (m<M) hUout[(size_t)m*256+col] = __float2bfloat16(acc[rf][t][r]);
      }
    }
}

// ---------------------------------------------------------------------------
// Fused gather + GRU step + next hU.  h stored fp16 between steps (rel 2^-11;
// round-13 calibration: bf16 h -> absmax 108; fp16 is 8x finer -> ~35).
// DO_HU=1: writes fp16 h + bf16 hU.  DO_HU=0 (last step): writes f32 h.
// ---------------------------------------------------------------------------
template<int GEXT, int DO_HU>
__global__ __launch_bounds__(256)
void mfma_gg(const __half* __restrict__ hprev, const bf16* __restrict__ hUprev,
             const int* __restrict__ bgraph, Feat fr,
             const short* __restrict__ Bz, const short* __restrict__ Bh,
             const short* __restrict__ Bze, const short* __restrict__ Bhe,
             const int* __restrict__ aidx, const int* __restrict__ gfm,
             const float* __restrict__ bzb, const float* __restrict__ bhb,
             Feat fz, Feat fh, const short* __restrict__ Bu,
             __half* __restrict__ houtH, float* __restrict__ houtF,
             bf16* __restrict__ hUout, int M)
{
  __shared__ float SH[32][260];
  __shared__ short SG[32][264];     // sumgh; reused as bf16 h-tile after barrier
  const int tid=threadIdx.x, lane=tid&63, wc=tid>>6;
  const int rbase = blockIdx.x<<5;
  const int koff = (lane>>4)<<3;

  // ---- Phase A: gather (h fp16 + hU bf16 streams) ----
  {
    const int c = lane<<2;
    #pragma unroll 2
    for (int s=0;s<8;s++){
      int lrow = (wc<<3) + s;
      int m = rbase + lrow;
      float4 sv = make_float4(0,0,0,0);
      float4 gv = make_float4(0,0,0,0);
      if (m < M){
        float4 fr4 = feat_eval4(fr, m, c);
        const int* bg = bgraph + (size_t)m*6;
        #pragma unroll
        for (int j=0;j<6;j++){
          int id = bg[j];
          uint2 hraw = *(const uint2*)(hprev + (size_t)id*256 + c);
          __half2 h01 = *(__half2*)&hraw.x;
          __half2 h23 = *(__half2*)&hraw.y;
          float2 f01 = __half22float2(h01);
          float2 f23 = __half22float2(h23);
          uint2  u2 = *(const uint2*)(hUprev + (size_t)id*256 + c);
          float u0=ubf(u2.x&0xffffu), u1=ubf(u2.x>>16);
          float u2f=ubf(u2.y&0xffffu), u3=ubf(u2.y>>16);
          sv.x+=f01.x; sv.y+=f01.y; sv.z+=f23.x; sv.w+=f23.y;
          gv.x += sigm(fr4.x+u0 )*f01.x;
          gv.y += sigm(fr4.y+u1 )*f01.y;
          gv.z += sigm(fr4.z+u2f)*f23.x;
          gv.w += sigm(fr4.w+u3 )*f23.y;
        }
      }
      *(float4*)&SH[lrow][c] = sv;
      uint2 p; p.x = pack2bf(gv.x,gv.y); p.y = pack2bf(gv.z,gv.w);
      *(uint2*)&SG[lrow][c] = p;
    }
  }
  __syncthreads();

  // ---- Phase B: GRU dual GEMM from LDS ----
  const int r0l = lane&15, r1l = r0l+16;
  const int r0 = rbase + r0l, r1 = rbase + r1l;
  f32x4 zero = {0.f,0.f,0.f,0.f};
  f32x4 accz[2][4], acch[2][4];
  #pragma unroll
  for (int rf=0;rf<2;rf++)
    #pragma unroll
    for (int t=0;t<4;t++){ accz[rf][t]=zero; acch[rf][t]=zero; }

  PRIO_HI;
  for (int kc=0;kc<8;kc++){
    bf16x8 a0h, a0l, a1h, a1l;
    build_a(&SH[r0l][kc*32+koff], a0h, a0l);
    build_a(&SH[r1l][kc*32+koff], a1h, a1l);
    bf16x8 s0 = *(const bf16x8*)&SG[r0l][kc*32+koff];
    bf16x8 s1 = *(const bf16x8*)&SG[r1l][kc*32+koff];
    #pragma unroll
    for (int t=0;t<4;t++){
      const short* pz = Bz + (((kc<<4)+(wc<<2)+t)<<10) + (lane<<4);
      const short* ph = Bh + (((kc<<4)+(wc<<2)+t)<<10) + (lane<<4);
      bf16x8 bzh = *(const bf16x8*)pz;
      bf16x8 bzl = *(const bf16x8*)(pz+8);
      bf16x8 bhh = *(const bf16x8*)ph;
      bf16x8 bhl = *(const bf16x8*)(ph+8);
      accz[0][t]=MFMA(a0h,bzh,accz[0][t],0,0,0);
      accz[1][t]=MFMA(a1h,bzh,accz[1][t],0,0,0);
      accz[0][t]=MFMA(a0l,bzh,accz[0][t],0,0,0);
      accz[1][t]=MFMA(a1l,bzh,accz[1][t],0,0,0);
      accz[0][t]=MFMA(a0h,bzl,accz[0][t],0,0,0);
      accz[1][t]=MFMA(a1h,bzl,accz[1][t],0,0,0);
      acch[0][t]=MFMA(s0,bhh,acch[0][t],0,0,0);
      acch[1][t]=MFMA(s1,bhh,acch[1][t],0,0,0);
      acch[0][t]=MFMA(s0,bhl,acch[0][t],0,0,0);
      acch[1][t]=MFMA(s1,bhl,acch[1][t],0,0,0);
    }
  }

  if (GEXT){
    int h0a=-1,h0b=-1,h0c=-1,h1a=-1,h1b=-1,h1c=-1;
    if (r0<M){ h0a=aidx[r0]; h0b=40+gfm[(size_t)r0*4+2]; h0c=44+gfm[(size_t)r0*4+3]; }
    if (r1<M){ h1a=aidx[r1]; h1b=40+gfm[(size_t)r1*4+2]; h1c=44+gfm[(size_t)r1*4+3]; }
    #pragma unroll
    for (int e=0;e<2;e++){
      bf16x8 ax0, ax1;
      #pragma unroll
      for (int j=0;j<8;j++){
        int d = e*32 + koff + j;
        ax0[j] = (d==h0a||d==h0b||d==h0c) ? (short)0x3F80 : (short)0;
        ax1[j] = (d==h1a||d==h1b||d==h1c) ? (short)0x3F80 : (short)0;
      }
      #pragma unroll
      for (int t=0;t<4;t++){
        const short* pe = Bze + (((e<<4)+(wc<<2)+t)<<10) + (lane<<4);
        const short* qe = Bhe + (((e<<4)+(wc<<2)+t)<<10) + (lane<<4);
        bf16x8 bzeh = *(const bf16x8*)pe;
        bf16x8 bzel = *(const bf16x8*)(pe+8);
        bf16x8 bheh = *(const bf16x8*)qe;
        bf16x8 bhel = *(const bf16x8*)(qe+8);
        accz[0][t]=MFMA(ax0,bzeh,accz[0][t],0,0,0);
        accz[1][t]=MFMA(ax1,bzeh,accz[1][t],0,0,0);
        accz[0][t]=MFMA(ax0,bzel,accz[0][t],0,0,0);
        accz[1][t]=MFMA(ax1,bzel,accz[1][t],0,0,0);
        acch[0][t]=MFMA(ax0,bheh,acch[0][t],0,0,0);
        acch[1][t]=MFMA(ax1,bheh,acch[1][t],0,0,0);
        acch[0][t]=MFMA(ax0,bhel,acch[0][t],0,0,0);
        acch[1][t]=MFMA(ax1,bhel,acch[1][t],0,0,0);
      }
    }
  }
  PRIO_LO;

  __syncthreads();   // all SG (sumgh) reads done before epilogue overwrites it

  // ---- Phase C: epilogue (per-row indices hoisted for the i/t path) ----
  const int rr = (lane>>4)<<2;
  const int cl = lane&15;
  int src8[8], pos8[8];
  if (!GEXT){
    #pragma unroll
    for (int rf=0;rf<2;rf++)
      #pragma unroll
      for (int r=0;r<4;r++){
        int m = rbase + rr + rf*16 + r;
        int mm = (m<M)? m : 0;
        src8[rf*4+r] = fz.didx [(size_t)mm*fz.dstride];
        pos8[rf*4+r] = fz.oidx0[(size_t)mm*fz.os0] + fz.oo0;
      }
  }
  #pragma unroll
  for (int rf=0;rf<2;rf++)
    #pragma unroll
    for (int t=0;t<4;t++){
      int col = (((wc<<2)+t)<<4) + cl;
      float fzb=0.f, fhb=0.f;
      if (GEXT){ fzb = bzb[col]; fhb = bhb[col]; }
      #pragma unroll
      for (int r=0;r<4;r++){
        int lrow = rr + rf*16 + r;
        int m = rbase + lrow;
        float v = 0.f;
        if (m<M){
          float fzv, fhv;
          if (GEXT){ fzv = fzb; fhv = fhb; }
          else {
            int i8 = rf*4+r;
            size_t so = (size_t)src8[i8]*256 + col;
            size_t po = (size_t)pos8[i8]*256 + col;
            fzv = fz.bias[col] + fz.dtab[so] + fz.otab[po];
            fhv = fh.bias[col] + fh.dtab[so] + fh.otab[po];
          }
          float z   = sigm  (accz[rf][t][r] + fzv);
          float pre = tanh_f(acch[rf][t][r] + fhv);
          float sh  = SH[lrow][col];
          v = (m==0) ? 0.f : ((1.f-z)*sh + z*pre);
          if (DO_HU) houtH[(size_t)m*256+col] = __float2half(v);
          else       houtF[(size_t)m*256+col] = v;
        }
        if (DO_HU) SG[lrow][col] = f2bf_s(v);
      }
    }

  // ---- Phase D: hU = bf16(h) @ Ur ----
  if (DO_HU){
    __syncthreads();
    f32x4 acc[2][4];
    #pragma unroll
    for (int rf=0;rf<2;rf++)
      #pragma unroll
      for (int t=0;t<4;t++) acc[rf][t]=zero;
    PRIO_HI;
    for (int kc=0;kc<8;kc++){
      bf16x8 a0 = *(const bf16x8*)&SG[r0l][kc*32+koff];
      bf16x8 a1 = *(const bf16x8*)&SG[r1l][kc*32+koff];
      #pragma unroll
      for (int t=0;t<4;t++){
        const short* p = Bu + (((kc<<4)+(wc<<2)+t)<<10) + (lane<<4);
        bf16x8 bh = *(const bf16x8*)p;
        bf16x8 bl = *(const bf16x8*)(p+8);
        acc[0][t]=MFMA(a0,bh,acc[0][t],0,0,0);
        acc[1][t]=MFMA(a1,bh,acc[1][t],0,0,0);
        acc[0][t]=MFMA(a0,bl,acc[0][t],0,0,0);
        acc[1][t]=MFMA(a1,bl,acc[1][t],0,0,0);
      }
    }
    PRIO_LO;
    #pragma unroll
    for (int rf=0;rf<2;rf++)
      #pragma unroll
      for (int t=0;t<4;t++){
        int col = (((wc<<2)+t)<<4) + cl;
        #pragma unroll
        for (int r=0;r<4;r++){
          int m = rbase + rr + rf*16 + r;
          if (m<M) hUout[(size_t)m*256+col] = __float2bfloat16(acc[rf][t][r]);
        }
      }
  }
}

// ---------------------------------------------------------------------------
// Vector GEMM kept only for the tiny Wroot (M=256, tanh epilogue).
// ---------------------------------------------------------------------------
template<int NG, int MODE>
__global__ __launch_bounds__(256)
void gemm256(const float* __restrict__ A1, const float* __restrict__ B1,
             const float* __restrict__ A2, const float* __restrict__ B2,
             float* __restrict__ Cf, int M, Feat f1, int mask0)
{
  __shared__ float As[NG][16][36];
  __shared__ float Bs[NG][16][260];
  const int tid = threadIdx.x;
  const int bm = blockIdx.x<<5;
  const int tm = (tid>>5)<<2;
  const int c0 = (tid&31)<<2;

  float acc[NG][4][8];
  #pragma unroll
  for (int g=0;g<NG;g++)
    #pragma unroll
    for (int i=0;i<4;i++)
      #pragma unroll
      for (int j=0;j<8;j++) acc[g][i][j]=0.f;

  const int t7  = tid & 127;
  const int alm = t7>>2;
  const int alk = (t7&3)<<2;
  const int arow = bm + alm;
  const int amat = (NG==2)? (tid>>7) : 0;
  const bool astage = (NG==2) || (tid<128);

  for (int k0=0;k0<256;k0+=16){
    float a0=0,a1=0,a2=0,a3=0;
    if (astage && arow<M){
      const float* src = (amat==0)? A1 : A2;
      float4 v = *(const float4*)(src + (size_t)arow*256 + k0 + alk);
      a0=v.x; a1=v.y; a2=v.z; a3=v.w;
    }
    float4 breg[NG][4];
    #pragma unroll
    for (int g=0; g<NG; g++){
      const float* B = (g==0)? B1 : B2;
      #pragma unroll
      for (int j=0;j<4;j++){
        int slot = tid + 256*j;
        int kb = slot>>6, nb = (slot&63)<<2;
        breg[g][j] = *(const float4*)(B + (size_t)(k0+kb)*256 + nb);
      }
    }
    __syncthreads();
    if (astage){
      As[amat][alk+0][alm]=a0; As[amat][alk+1][alm]=a1;
      As[amat][alk+2][alm]=a2; As[amat][alk+3][alm]=a3;
    }
    #pragma unroll
    for (int g=0; g<NG; g++){
      #pragma unroll
      for (int j=0;j<4;j++){
        int slot = tid + 256*j;
        int kb = slot>>6, nb = (slot&63)<<2;
        *(float4*)&Bs[g][kb][nb] = breg[g][j];
      }
    }
    __syncthreads();
    #pragma unroll
    for (int k=0;k<16;k++){
      #pragma unroll
      for (int g=0;g<NG;g++){
        float4 av = *(const float4*)&As[g][k][tm];
        float4 b0 = *(const float4*)&Bs[g][k][c0];
        float4 b1 = *(const float4*)&Bs[g][k][c0+128];
        float a_[4]={av.x,av.y,av.z,av.w};
        float b_[8]={b0.x,b0.y,b0.z,b0.w,b1.x,b1.y,b1.z,b1.w};
        #pragma unroll
        for (int i=0;i<4;i++)
          #pragma unroll
          for (int j=0;j<8;j++)
            acc[g][i][j] = fmaf(a_[i], b_[j], acc[g][i][j]);
      }
    }
  }

  #pragma unroll
  for (int i=0;i<4;i++){
    int m = bm + tm + i;
    if (m >= M) continue;
    #pragma unroll
    for (int half=0; half<2; half++){
      int c = c0 + half*128;
      float4 r;
      float* rr = &r.x;
      float4 ft = feat_eval4(f1, m, c);
      float fv[4]={ft.x,ft.y,ft.z,ft.w};
      #pragma unroll
      for (int j=0;j<4;j++){
        float s = acc[0][i][half*4+j] + (NG>1?acc[1][i][half*4+j]:0.f) + fv[j];
        float v = (MODE==1)? fmaxf(s,0.f) : tanhf(s);
        if (MODE==1 && mask0 && m==0) v = 0.f;
        rr[j] = v;
      }
      *(float4*)(Cf + (size_t)m*256+c) = r;
    }
  }
}

// ---------------------------------------------------------------------------
extern "C" void kernel_launch(void* const* d_in, const int* in_sizes, int n_in,
                              void* d_out, int out_size, void* d_ws, size_t ws_size,
                              hipStream_t stream)
{
  const int* t_fnode  = (const int*)d_in[0];
  const int* t_fmess  = (const int*)d_in[1];
  const int* t_agraph = (const int*)d_in[2];
  const int* t_bgraph = (const int*)d_in[3];
  const int* t_cgraph = (const int*)d_in[4];
  const int* g_fnode  = (const int*)d_in[5];
  const int* g_fmess  = (const int*)d_in[6];
  const int* g_agraph = (const int*)d_in[7];
  const int* g_bgraph = (const int*)d_in[8];
  const int* roots    = (const int*)d_in[9];
  const float* E_c     = (const float*)d_in[10];
  const float* E_i     = (const float*)d_in[11];
  const float* Wc_w    = (const float*)d_in[12];
  const float* Wc_b    = (const float*)d_in[13];
  const float* Wi_w    = (const float*)d_in[14];
  const float* Wi_b    = (const float*)d_in[15];
  const float* Wroot_w = (const float*)d_in[16];
  const float* Wroot_b = (const float*)d_in[17];
  const float* t_Wo_w  = (const float*)d_in[18];
  const float* t_Wo_b  = (const float*)d_in[19];
  const float* t_Wz_w  = (const float*)d_in[20];
  const float* t_Wz_b  = (const float*)d_in[21];
  const float* t_Wr_w  = (const float*)d_in[22];
  const float* t_Ur_w  = (const float*)d_in[23];
  const float* t_Ur_b  = (const float*)d_in[24];
  const float* t_Wh_w  = (const float*)d_in[25];
  const float* t_Wh_b  = (const float*)d_in[26];
  const float* i_Wo_w  = (const float*)d_in[27];
  const float* i_Wo_b  = (const float*)d_in[28];
  const float* i_Wz_w  = (const float*)d_in[29];
  const float* i_Wz_b  = (const float*)d_in[30];
  const float* i_Wr_w  = (const float*)d_in[31];
  const float* i_Ur_w  = (const float*)d_in[32];
  const float* i_Ur_b  = (const float*)d_in[33];
  const float* i_Wh_w  = (const float*)d_in[34];
  const float* i_Wh_b  = (const float*)d_in[35];
  const float* g_Wo_w  = (const float*)d_in[36];
  const float* g_Wo_b  = (const float*)d_in[37];
  const float* g_Wz_w  = (const float*)d_in[38];
  const float* g_Wz_b  = (const float*)d_in[39];
  const float* g_Wr_w  = (const float*)d_in[40];
  const float* g_Ur_w  = (const float*)d_in[41];
  const float* g_Ur_b  = (const float*)d_in[42];
  const float* g_Wh_w  = (const float*)d_in[43];
  const float* g_Wh_b  = (const float*)d_in[44];

  float* out        = (float*)d_out;
  float* out_hroot  = out;
  float* out_htree  = out + (size_t)65536;
  float* out_hinter = out + (size_t)65536 + 2048000;
  float* out_hatom  = out + (size_t)65536 + 2048000 + 2048000;

  // ---- workspace (~162.3 MB) ------------------------------------------------
  char* base = (char*)d_ws;
  int*    aidx = (int*)base;                               // 262144 B reserved
  short*  SP   = (short*)(base + 262144);                  // plane region (8 MB)
  __half* hH_A = (__half*)(base + 262144 + 8388608);       // h fp16 A (25.6 MB)
  __half* hH_B = hH_A + (size_t)12800000;                  // h fp16 B
  bf16*   hU_A = (bf16*)(hH_B + (size_t)12800000);         // hU bf16 A
  bf16*   hU_B = hU_A + (size_t)12800000;                  // hU bf16 B
  float*  W0   = (float*)(hU_B + (size_t)12800000);        // f32 h + scratch (51.2 MB)

  auto GP = [&](int i)->short* { return SP + (size_t)i*131072; };
  short* EZ = SP + (size_t)9*131072;
  short* EH = EZ + 32768;
  auto HP = [&](int j)->short* { return EH + 32768 + (size_t)j*131072; };
  short* P2 = EH + 32768 + (size_t)6*131072;
  auto PP = [&](int j)->short* { return P2 + (size_t)j*131072; };

  // scratch sub-buffers (f32 views of dead fp16/bf16 ping-pong regions;
  // each region = 25.6 MB = 25000 f32 rows; lifetimes traced per phase)
  float* hHAf = (float*)hH_A;
  float* hHBf = (float*)hH_B;
  float* hUAf = (float*)hU_A;
  float* neibG    = hHAf;                     // 25000 rows (post g-GRU, hH dead)
  float* hatom    = hUAf;                     // 25000 rows (consumed pre I-GRU)
  float* neib_t   = hHBf;                     // 8000 (consumed pre I-GRU)
  float* hn_i     = W0 + (size_t)16000*256;   // 8000 (alive through I Wo)
  float* hnWz     = W0 + (size_t)24000*256;   // 8000
  float* hnWr     = W0 + (size_t)32000*256;   // 8000
  float* hnWh     = W0 + (size_t)40000*256;   // 8000 (ends 48000 <= 50000)
  float* nei_i    = hHAf;                     // 8000 (post I-GRU)
  float* hinter   = hHBf;                     // 8000 (consumed by T prep)
  float* hn_t     = W0 + (size_t)16000*256;   // 8000 (overwrites dead hn_i)
  float* nei_t    = hHAf;                     // 8000 (post T-GRU)
  float* hn_roots = hHBf;                     // 256 (hinter dead after T prep)
  float* nei_root = hHBf + (size_t)256*256;   // 256

  (void)in_sizes; (void)n_in; (void)out_size; (void)ws_size;

  // ---- weight split/swizzle: one batched launch ----------------------------
  SJobs js;
  js.j[0]  = { g_Ur_w,                    GP(0), 256, 0 };
  js.j[1]  = { g_Wz_w + (size_t)64*256,   GP(1), 256, 0 };
  js.j[2]  = { g_Wh_w + (size_t)64*256,   GP(2), 256, 0 };
  js.j[3]  = { i_Ur_w,                    GP(3), 256, 0 };
  js.j[4]  = { i_Wz_w + (size_t)276*256,  GP(4), 256, 0 };
  js.j[5]  = { i_Wh_w + (size_t)276*256,  GP(5), 256, 0 };
  js.j[6]  = { t_Ur_w,                    GP(6), 256, 0 };
  js.j[7]  = { t_Wz_w + (size_t)276*256,  GP(7), 256, 0 };
  js.j[8]  = { t_Wh_w + (size_t)276*256,  GP(8), 256, 0 };
  js.j[9]  = { g_Wz_w,                    EZ,     64, 0 };
  js.j[10] = { g_Wh_w,                    EH,     64, 0 };
  js.j[11] = { i_Wz_w,                    HP(0), 256, 0 };
  js.j[12] = { i_Wr_w,                    HP(1), 256, 0 };
  js.j[13] = { i_Wh_w,                    HP(2), 256, 0 };
  js.j[14] = { t_Wz_w,                    HP(3), 256, 0 };
  js.j[15] = { t_Wr_w,                    HP(4), 256, 0 };
  js.j[16] = { t_Wh_w,                    HP(5), 256, 0 };
  js.j[17] = { Wi_w,                      PP(0), 256, 0 };
  js.j[18] = { Wi_w + (size_t)256*256,    PP(1), 256, 0 };
  js.j[19] = { Wc_w,                      PP(2), 256, 0 };
  js.j[20] = { Wc_w + (size_t)256*256,    PP(3), 256, 0 };
  js.j[21] = { i_Wo_w,                    PP(4), 256, 0 };
  js.j[22] = { i_Wo_w + (size_t)256*256,  PP(5), 256, 0 };
  js.j[23] = { t_Wo_w,                    PP(6), 256, 0 };
  js.j[24] = { t_Wo_w + (size_t)256*256,  PP(7), 256, 0 };
  js.j[25] = { g_Wo_w + (size_t)40*256,   PP(8), 256, 0 };
  k_splitw_b<<<dim3(256,26),256,0,stream>>>(js);

  // ---- feature descriptors -------------------------------------------------
  Feat fzg{}; fzg.otab=g_Wz_w; fzg.oidx0=aidx;      fzg.os0=1; fzg.oo0=0;
              fzg.oidx1=g_fmess+2; fzg.os1=4; fzg.oo1=40;
              fzg.oidx2=g_fmess+3; fzg.os2=4; fzg.oo2=44; fzg.bias=g_Wz_b;
  Feat frg = fzg; frg.otab=g_Wr_w; frg.bias=g_Ur_b;
  Feat fhg = fzg; fhg.otab=g_Wh_w; fhg.bias=g_Wh_b;

  Feat fzi{}; fzi.dtab=hnWz; fzi.didx=t_fmess; fzi.dstride=3;
              fzi.otab=i_Wz_w; fzi.oidx0=t_fmess+2; fzi.os0=3; fzi.oo0=256; fzi.bias=i_Wz_b;
  Feat fri = fzi; fri.dtab=hnWr; fri.otab=i_Wr_w; fri.bias=i_Ur_b;
  Feat fhi = fzi; fhi.dtab=hnWh; fhi.otab=i_Wh_w; fhi.bias=i_Wh_b;

  Feat fzt = fzi; fzt.otab=t_Wz_w; fzt.bias=t_Wz_b;
  Feat frt = fri; frt.otab=t_Wr_w; frt.bias=t_Ur_b;
  Feat fht = fhi; fht.otab=t_Wh_w; fht.bias=t_Wh_b;

  Feat fnone{};

  // ---- GRU driver: step1+hU (fp16 h), 3x fused, final -> f32 W0 ------------
  auto run_gru = [&](int M, const int* bgraph, int p, bool gext,
                     Feat fz, Feat fr, Feat fh)->float* {
    int gb32 = (M+31)/32;
    const short* Bu = GP(p*3+0);
    const short* Bz = GP(p*3+1);
    const short* Bh = GP(p*3+2);
    k_step1hu<<<gb32,256,0,stream>>>(fz, fh, Bu, hH_A, hU_A, M);
    __half* hA = hH_A;  bf16* uA = hU_A;
    __half* hB = hH_B;  bf16* uB = hU_B;
    for (int d=0; d<4; ++d){
      if (d<3){
        if (gext)
          mfma_gg<1,1><<<gb32,256,0,stream>>>(hA, uA, bgraph, fr, Bz, Bh,
              EZ, EH, aidx, g_fmess, g_Wz_b, g_Wh_b, fnone, fnone, Bu,
              hB, nullptr, uB, M);
        else
          mfma_gg<0,1><<<gb32,256,0,stream>>>(hA, uA, bgraph, fr, Bz, Bh,
              nullptr,nullptr,nullptr,nullptr,nullptr,nullptr, fz, fh, Bu,
              hB, nullptr, uB, M);
      } else {
        if (gext)
          mfma_gg<1,0><<<gb32,256,0,stream>>>(hA, uA, bgraph, fr, Bz, Bh,
              EZ, EH, aidx, g_fmess, g_Wz_b, g_Wh_b, fnone, fnone, nullptr,
              nullptr, W0, nullptr, M);
        else
          mfma_gg<0,0><<<gb32,256,0,stream>>>(hA, uA, bgraph, fr, Bz, Bh,
              nullptr,nullptr,nullptr,nullptr,nullptr,nullptr, fz, fh, nullptr,
              nullptr, W0, nullptr, M);
      }
      __half* th=hA; hA=hB; hB=th;
      bf16*   tu=uA; uA=uB; uB=tu;
    }
    return W0;
  };

  // ==== Phase G: atom graph MPN ============================================
  k_aidx<<<(MA_+255)/256,256,0,stream>>>(g_fnode, g_fmess, aidx, MA_);
  float* hg = run_gru(MA_, g_bgraph, 0, true, fzg, frg, fhg);
  k_gsum4<<<(NA_+3)/4,256,0,stream>>>(hg, g_agraph, nullptr, 6, 6, neibG, NA_);
  Feat fWo{}; fWo.otab=g_Wo_w; fWo.oidx0=g_fnode; fWo.os0=1; fWo.oo0=0; fWo.bias=g_Wo_b;
  mfma_proj<1><<<(NA_+31)/32,256,0,stream>>>(neibG, nullptr, 1, nullptr,
      PP(8), nullptr, hatom, out_hatom, fWo, 1, NA_);

  // ==== Phase I prep ========================================================
  k_gsum4<<<(NT_+3)/4,256,0,stream>>>(hatom, t_cgraph, nullptr, 12, 12, neib_t, NT_);
  Feat fbWi{}; fbWi.bias=Wi_b;
  mfma_proj<2><<<NT_/32,256,0,stream>>>(E_i, t_fnode+1, 2, neib_t,
      PP(0), PP(1), hn_i, nullptr, fbWi, 0, NT_);
  mfma_mm<<<NT_/32,256,0,stream>>>(hn_i, HP(0), hnWz, NT_);
  mfma_mm<<<NT_/32,256,0,stream>>>(hn_i, HP(1), hnWr, NT_);
  mfma_mm<<<NT_/32,256,0,stream>>>(hn_i, HP(2), hnWh, NT_);

  // ==== Phase I GRU =========================================================
  float* hi = run_gru(MT_, t_bgraph, 1, false, fzi, fri, fhi);
  k_gsum4<<<(NT_+3)/4,256,0,stream>>>(hi, t_agraph, nullptr, 6, 6, nei_i, NT_);
  Feat fbWoi{}; fbWoi.bias=i_Wo_b;
  mfma_proj<2><<<NT_/32,256,0,stream>>>(hn_i, nullptr, 1, nei_i,
      PP(4), PP(5), hinter, out_hinter, fbWoi, 1, NT_);

  // ==== Phase T prep ========================================================
  Feat fbWc{}; fbWc.bias=Wc_b;
  mfma_proj<2><<<NT_/32,256,0,stream>>>(E_c, t_fnode, 2, hinter,
      PP(2), PP(3), hn_t, nullptr, fbWc, 0, NT_);
  mfma_mm<<<NT_/32,256,0,stream>>>(hn_t, HP(3), hnWz, NT_);
  mfma_mm<<<NT_/32,256,0,stream>>>(hn_t, HP(4), hnWr, NT_);
  mfma_mm<<<NT_/32,256,0,stream>>>(hn_t, HP(5), hnWh, NT_);

  // ==== Phase T GRU =========================================================
  float* ht = run_gru(MT_, t_bgraph, 2, false, fzt, frt, fht);
  k_gsum4<<<(NT_+3)/4,256,0,stream>>>(ht, t_agraph, nullptr, 6, 6, nei_t, NT_);
  Feat fbWot{}; fbWot.bias=t_Wo_b;
  mfma_proj<2><<<NT_/32,256,0,stream>>>(hn_t, nullptr, 1, nei_t,
      PP(6), PP(7), out_htree, nullptr, fbWot, 1, NT_);

  // ==== Root ================================================================
  k_gsum4<<<(NROOT_+3)/4,256,0,stream>>>(hn_t, roots, nullptr, 1, 1, hn_roots, NROOT_);
  k_gsum4<<<(NROOT_+3)/4,256,0,stream>>>(ht, t_agraph, roots, 6, 6, nei_root, NROOT_);
  Feat fbWr{}; fbWr.bias=Wroot_b;
  gemm256<2,2><<<NROOT_/32,256,0,stream>>>(hn_roots, Wroot_w, nei_root,
      Wroot_w + (size_t)256*256, out_hroot, NROOT_, fbWr, 0);
}

// Round 16
// 1783.582 us; speedup vs baseline: 1.0421x; 1.0171x over previous
//
#include <hip/hip_runtime.h>
#include <hip/hip_bf16.h>
#include <hip/hip_fp16.h>
#include <math.h>

typedef __hip_bfloat16 bf16;
typedef __attribute__((ext_vector_type(8))) short  bf16x8;
typedef __attribute__((ext_vector_type(4))) float  f32x4;

#define NT_ 8000
#define MT_ 16000
#define NA_ 25000
#define MA_ 50000
#define NROOT_ 256

// ---------------------------------------------------------------------------
struct Feat {
  const float* dtab; const int* didx; int dstride;
  const float* otab;
  const int* oidx0; int os0; int oo0;
  const int* oidx1; int os1; int oo1;
  const int* oidx2; int os2; int oo2;
  const float* bias;
};

// Fast HW-native transcendentals (v_exp_f32 + v_rcp_f32; rel err ~1e-6).
__device__ __forceinline__ float rcpf_(float x){ return __builtin_amdgcn_rcpf(x); }
__device__ __forceinline__ float sigm(float x){ return rcpf_(1.0f + __expf(-x)); }
__device__ __forceinline__ float tanh_f(float x){
  float t = __expf(2.0f*x);
  return 1.0f - 2.0f*rcpf_(t + 1.0f);
}

__device__ __forceinline__ float ubf(unsigned int u){ union{unsigned int i; float f;} x; x.i = u<<16; return x.f; }
__device__ __forceinline__ short f2bf_s(float f){
  bf16 b = __float2bfloat16(f);
  return *(short*)&b;
}
__device__ __forceinline__ float bfs2f(short s){ return ubf((unsigned short)s); }
// packed record: (fp16(h) << 16) | bf16(hU)   -- numerics identical to r15
__device__ __forceinline__ float rec_h(unsigned int u){
  return __half2float(__ushort_as_half((unsigned short)(u>>16)));
}
__device__ __forceinline__ float rec_u(unsigned int u){ return ubf(u&0xffffu); }

__device__ __forceinline__ void acc4(float4& v, const float* p){
  float4 t = *(const float4*)p;
  v.x+=t.x; v.y+=t.y; v.z+=t.z; v.w+=t.w;
}
__device__ __forceinline__ float4 feat_eval4(const Feat& f, int m, int n){
  float4 v = make_float4(0,0,0,0);
  if (f.bias) acc4(v, f.bias + n);
  if (f.dtab) acc4(v, f.dtab + (size_t)f.didx[(size_t)m*f.dstride]*256 + n);
  if (f.otab){
    acc4(v, f.otab + (size_t)(f.oidx0[(size_t)m*f.os0]+f.oo0)*256 + n);
    if (f.oidx1) acc4(v, f.otab + (size_t)(f.oidx1[(size_t)m*f.os1]+f.oo1)*256 + n);
    if (f.oidx2) acc4(v, f.otab + (size_t)(f.oidx2[(size_t)m*f.os2]+f.oo2)*256 + n);
  }
  return v;
}
__device__ __forceinline__ float feat_eval(const Feat& f, int m, int n){
  float v = 0.0f;
  if (f.bias) v += f.bias[n];
  if (f.dtab) v += f.dtab[(size_t)f.didx[(size_t)m*f.dstride]*256 + n];
  if (f.otab){
    v += f.otab[((size_t)(f.oidx0[(size_t)m*f.os0]+f.oo0))*256 + n];
    if (f.oidx1) v += f.otab[((size_t)(f.oidx1[(size_t)m*f.os1]+f.oo1))*256 + n];
    if (f.oidx2) v += f.otab[((size_t)(f.oidx2[(size_t)m*f.os2]+f.oo2))*256 + n];
  }
  return v;
}

// ---------------------------------------------------------------------------
__global__ void k_aidx(const int* __restrict__ g_fnode, const int* __restrict__ g_fmess,
                       int* __restrict__ aidx, int M){
  int m = blockIdx.x*blockDim.x + threadIdx.x;
  if (m<M) aidx[m] = g_fnode[g_fmess[(size_t)m*4]];
}

// Batched weight split/swizzle.
struct SJob { const float* src; short* dst; int nrow; int pad; };
struct SJobs { SJob j[26]; };
__global__ void k_splitw_b(SJobs js){
  SJob jb = js.j[blockIdx.y];
  int idx = blockIdx.x*256 + threadIdx.x;
  if (idx >= jb.nrow*256) return;
  int k = idx>>8, n = idx&255;
  float w = jb.src[idx];
  int base = (((k>>5)*16 + (n>>4))<<10) + (((n&15) + (((k>>3)&3)<<4))<<4) + (k&7);
  short h = f2bf_s(w);
  jb.dst[base]   = h;
  jb.dst[base+8] = f2bf_s(w - bfs2f(h));
}

// dst[m] = sum_j src[idx[(rowsel?rowsel[m]:m)*istride + j]]   (wave per row)
__global__ void k_gsum4(const float* __restrict__ src, const int* __restrict__ idx,
                        const int* __restrict__ rowsel, int J, int istride,
                        float* __restrict__ dst, int M){
  int wid = (blockIdx.x<<2) + (threadIdx.x>>6);
  if (wid>=M) return;
  int c = (threadIdx.x&63)<<2;
  int r = rowsel ? rowsel[wid] : wid;
  float4 s = make_float4(0,0,0,0);
  for (int j=0;j<J;j++){
    int id = idx[(size_t)r*istride+j];
    acc4(s, src + (size_t)id*256 + c);
  }
  *(float4*)(dst + (size_t)wid*256 + c) = s;
}

// ---------------------------------------------------------------------------
// MFMA common. Block = 256 thr = 4 waves; wave wc covers cols [wc*64,+64)
// (4 tiles); block covers rows [bid*32,+32) as 2 A-frags.
// ---------------------------------------------------------------------------
__device__ __forceinline__ void build_a(const float* p, bf16x8& hi, bf16x8& lo){
  float4 v0 = *(const float4*)p;
  float4 v1 = *(const float4*)(p+4);
  float vv[8]={v0.x,v0.y,v0.z,v0.w,v1.x,v1.y,v1.z,v1.w};
  #pragma unroll
  for (int j=0;j<8;j++){
    short h = f2bf_s(vv[j]);
    hi[j]=h;
    lo[j]=f2bf_s(vv[j]-bfs2f(h));
  }
}

#define MFMA __builtin_amdgcn_mfma_f32_16x16x32_bf16
#define PRIO_HI __builtin_amdgcn_s_setprio(1)
#define PRIO_LO __builtin_amdgcn_s_setprio(0)

// out = A @ W (bf16x3), f32 out (hnW tables).
__global__ __launch_bounds__(256)
void mfma_mm(const float* __restrict__ A, const short* __restrict__ Bp,
             float* __restrict__ outf, int M)
{
  const int tid=threadIdx.x, lane=tid&63, wc=tid>>6;
  const int rbase = blockIdx.x<<5;
  const int r0 = rbase + (lane&15), r1 = r0 + 16;
  const int koff = (lane>>4)<<3;
  f32x4 zero = {0.f,0.f,0.f,0.f};
  f32x4 acc[2][4];
  #pragma unroll
  for (int rf=0;rf<2;rf++)
    #pragma unroll
    for (int t=0;t<4;t++) acc[rf][t]=zero;

  PRIO_HI;
  for (int kc=0;kc<8;kc++){
    bf16x8 a0h={0,0,0,0,0,0,0,0}, a0l=a0h, a1h=a0h, a1l=a0h;
    if (r0<M) build_a(A + (size_t)r0*256 + kc*32 + koff, a0h, a0l);
    if (r1<M) build_a(A + (size_t)r1*256 + kc*32 + koff, a1h, a1l);
    #pragma unroll
    for (int t=0;t<4;t++){
      const short* p = Bp + (((kc<<4)+(wc<<2)+t)<<10) + (lane<<4);
      bf16x8 bh = *(const bf16x8*)p;
      bf16x8 bl = *(const bf16x8*)(p+8);
      acc[0][t]=MFMA(a0h,bh,acc[0][t],0,0,0);
      acc[1][t]=MFMA(a1h,bh,acc[1][t],0,0,0);
      acc[0][t]=MFMA(a0l,bh,acc[0][t],0,0,0);
      acc[1][t]=MFMA(a1l,bh,acc[1][t],0,0,0);
      acc[0][t]=MFMA(a0h,bl,acc[0][t],0,0,0);
      acc[1][t]=MFMA(a1h,bl,acc[1][t],0,0,0);
    }
  }
  PRIO_LO;
  const int rr = rbase + ((lane>>4)<<2);
  const int cl = lane&15;
  #pragma unroll
  for (int rf=0;rf<2;rf++)
    #pragma unroll
    for (int t=0;t<4;t++){
      int col = (((wc<<2)+t)<<4) + cl;
      #pragma unroll
      for (int r=0;r<4;r++){
        int m = rr + rf*16 + r;
        if (m<M) outf[(size_t)m*256+col] = acc[rf][t][r];
      }
    }
}

// ---------------------------------------------------------------------------
// Projection GEMM: out = relu(A1@B1 [+ A2@B2] + feat(f1)); optional row-0 mask.
// ---------------------------------------------------------------------------
template<int NG>
__global__ __launch_bounds__(256)
void mfma_proj(const float* __restrict__ A1, const int* __restrict__ a1idx, int a1s,
               const float* __restrict__ A2,
               const short* __restrict__ B1p, const short* __restrict__ B2p,
               float* __restrict__ outf, float* __restrict__ outf2,
               Feat f1, int mask0, int M)
{
  const int tid=threadIdx.x, lane=tid&63, wc=tid>>6;
  const int rbase = blockIdx.x<<5;
  const int r0 = rbase + (lane&15), r1 = r0 + 16;
  const int koff = (lane>>4)<<3;
  const float* p0 = (r0<M) ? A1 + (size_t)(a1idx? a1idx[(size_t)r0*a1s] : r0)*256 : nullptr;
  const float* p1 = (r1<M) ? A1 + (size_t)(a1idx? a1idx[(size_t)r1*a1s] : r1)*256 : nullptr;
  f32x4 zero = {0.f,0.f,0.f,0.f};
  f32x4 acc[2][4];
  #pragma unroll
  for (int rf=0;rf<2;rf++)
    #pragma unroll
    for (int t=0;t<4;t++) acc[rf][t]=zero;

  PRIO_HI;
  for (int kc=0;kc<8;kc++){
    bf16x8 a0h={0,0,0,0,0,0,0,0}, a0l=a0h, a1h=a0h, a1l=a0h;
    bf16x8 c0h=a0h, c0l=a0h, c1h=a0h, c1l=a0h;
    if (p0) build_a(p0 + kc*32 + koff, a0h, a0l);
    if (p1) build_a(p1 + kc*32 + koff, a1h, a1l);
    if (NG==2){
      if (r0<M) build_a(A2 + (size_t)r0*256 + kc*32 + koff, c0h, c0l);
      if (r1<M) build_a(A2 + (size_t)r1*256 + kc*32 + koff, c1h, c1l);
    }
    #pragma unroll
    for (int t=0;t<4;t++){
      const short* p = B1p + (((kc<<4)+(wc<<2)+t)<<10) + (lane<<4);
      bf16x8 bh = *(const bf16x8*)p;
      bf16x8 bl = *(const bf16x8*)(p+8);
      acc[0][t]=MFMA(a0h,bh,acc[0][t],0,0,0);
      acc[1][t]=MFMA(a1h,bh,acc[1][t],0,0,0);
      acc[0][t]=MFMA(a0l,bh,acc[0][t],0,0,0);
      acc[1][t]=MFMA(a1l,bh,acc[1][t],0,0,0);
      acc[0][t]=MFMA(a0h,bl,acc[0][t],0,0,0);
      acc[1][t]=MFMA(a1h,bl,acc[1][t],0,0,0);
      if (NG==2){
        const short* q = B2p + (((kc<<4)+(wc<<2)+t)<<10) + (lane<<4);
        bf16x8 dh = *(const bf16x8*)q;
        bf16x8 dl = *(const bf16x8*)(q+8);
        acc[0][t]=MFMA(c0h,dh,acc[0][t],0,0,0);
        acc[1][t]=MFMA(c1h,dh,acc[1][t],0,0,0);
        acc[0][t]=MFMA(c0l,dh,acc[0][t],0,0,0);
        acc[1][t]=MFMA(c1l,dh,acc[1][t],0,0,0);
        acc[0][t]=MFMA(c0h,dl,acc[0][t],0,0,0);
        acc[1][t]=MFMA(c1h,dl,acc[1][t],0,0,0);
      }
    }
  }
  PRIO_LO;
  const int rr = rbase + ((lane>>4)<<2);
  const int cl = lane&15;
  #pragma unroll
  for (int rf=0;rf<2;rf++)
    #pragma unroll
    for (int t=0;t<4;t++){
      int col = (((wc<<2)+t)<<4) + cl;
      #pragma unroll
      for (int r=0;r<4;r++){
        int m = rr + rf*16 + r;
        if (m>=M) continue;
        float v = acc[rf][t][r] + feat_eval(f1, m, col);
        v = fmaxf(v, 0.0f);
        if (mask0 && m==0) v = 0.0f;
        outf[(size_t)m*256+col] = v;
        if (outf2) outf2[(size_t)m*256+col] = v;
      }
    }
}

// ---------------------------------------------------------------------------
// GRU step 1 (h0=0): h = sigmoid(fz)*tanh(fh); bf16 tile in LDS, fp16 bits in
// registers; hU = bf16(h)@Ur; emit packed record (fp16(h)<<16 | bf16(hU)).
// ---------------------------------------------------------------------------
__global__ __launch_bounds__(256)
void k_step1hu(Feat fz, Feat fh, const short* __restrict__ Bu,
               unsigned int* __restrict__ recout, int M)
{
  __shared__ short Hs[32][264];
  const int tid=threadIdx.x, lane=tid&63, wc=tid>>6;
  const int rbase = blockIdx.x<<5;
  const int rr = (lane>>4)<<2;
  const int cl = lane&15;
  const int koff = (lane>>4)<<3;
  unsigned short hreg[32];

  #pragma unroll
  for (int rf=0;rf<2;rf++)
    #pragma unroll
    for (int t=0;t<4;t++){
      int col = (((wc<<2)+t)<<4) + cl;
      #pragma unroll
      for (int r=0;r<4;r++){
        int lrow = rr + rf*16 + r;
        int m = rbase + lrow;
        float v = 0.f;
        if (m<M && m!=0)
          v = sigm(feat_eval(fz,m,col))*tanh_f(feat_eval(fh,m,col));
        Hs[lrow][col]=f2bf_s(v);
        hreg[(((rf<<2)+t)<<2)+r] = __half_as_ushort(__float2half(v));
      }
    }
  __syncthreads();
  const int r0l = lane&15, r1l = r0l+16;
  f32x4 zero = {0.f,0.f,0.f,0.f};
  f32x4 acc[2][4];
  #pragma unroll
  for (int rf=0;rf<2;rf++)
    #pragma unroll
    for (int t=0;t<4;t++) acc[rf][t]=zero;
  PRIO_HI;
  for (int kc=0;kc<8;kc++){
    bf16x8 a0 = *(const bf16x8*)&Hs[r0l][kc*32+koff];
    bf16x8 a1 = *(const bf16x8*)&Hs[r1l][kc*32+koff];
    #pragma unroll
    for (int t=0;t<4;t++){
      const short* p = Bu + (((kc<<4)+(wc<<2)+t)<<10) + (lane<<4);
      bf16x8 bh = *(const bf16x8*)p;
      bf16x8 bl = *(const bf16x8*)(p+8);
      acc[0][t]=MFMA(a0,bh,acc[0][t],0,0,0);
      acc[1][t]=MFMA(a1,bh,acc[1][t],0,0,0);
      acc[0][t]=MFMA(a0,bl,acc[0][t],0,0,0);
      acc[1][t]=MFMA(a1,bl,acc[1][t],0,0,0);
    }
  }
  PRIO_LO;
  #pragma unroll
  for (int rf=0;rf<2;rf++)
    #pragma unroll
    for (int t=0;t<4;t++){
      int col = (((wc<<2)+t)<<4) + cl;
      #pragma unroll
      for (int r=0;r<4;r++){
        int m = rbase + rr + rf*16 + r;
        if (m<M){
          unsigned int hw = hreg[(((rf<<2)+t)<<2)+r];
          unsigned int uw = (unsigned short)f2bf_s(acc[rf][t][r]);
          recout[(size_t)m*256+col] = (hw<<16) | uw;
        }
      }
    }
}

// ---------------------------------------------------------------------------
// Fused gather + GRU step + next hU, packed-record I/O.
// Record: (fp16(h)<<16 | bf16(hU)) -- one uint4 load/neighbor in gather.
// DO_HU=1: emits next packed record.  DO_HU=0 (last step): writes f32 h.
// ---------------------------------------------------------------------------
template<int GEXT, int DO_HU>
__global__ __launch_bounds__(256)
void mfma_gg(const unsigned int* __restrict__ recprev,
             const int* __restrict__ bgraph, Feat fr,
             const short* __restrict__ Bz, const short* __restrict__ Bh,
             const short* __restrict__ Bze, const short* __restrict__ Bhe,
             const int* __restrict__ aidx, const int* __restrict__ gfm,
             const float* __restrict__ bzb, const float* __restrict__ bhb,
             Feat fz, Feat fh, const short* __restrict__ Bu,
             unsigned int* __restrict__ recout, float* __restrict__ houtF, int M)
{
  __shared__ float SH[32][260];
  __shared__ short SG[32][264];     // sumgh; reused as bf16 h-tile after barrier
  const int tid=threadIdx.x, lane=tid&63, wc=tid>>6;
  const int rbase = blockIdx.x<<5;
  const int koff = (lane>>4)<<3;

  // ---- Phase A: gather from packed records (1 uint4 load per neighbor) ----
  {
    const int c = lane<<2;
    #pragma unroll 2
    for (int s=0;s<8;s++){
      int lrow = (wc<<3) + s;
      int m = rbase + lrow;
      float4 sv = make_float4(0,0,0,0);
      float4 gv = make_float4(0,0,0,0);
      if (m < M){
        float4 fr4 = feat_eval4(fr, m, c);
        const int* bg = bgraph + (size_t)m*6;
        #pragma unroll
        for (int j=0;j<6;j++){
          int id = bg[j];
          uint4 u = *(const uint4*)(recprev + (size_t)id*256 + c);
          float h0=rec_h(u.x), h1=rec_h(u.y), h2=rec_h(u.z), h3=rec_h(u.w);
          float u0=rec_u(u.x), u1=rec_u(u.y), u2f=rec_u(u.z), u3=rec_u(u.w);
          sv.x+=h0; sv.y+=h1; sv.z+=h2; sv.w+=h3;
          gv.x += sigm(fr4.x+u0 )*h0;
          gv.y += sigm(fr4.y+u1 )*h1;
          gv.z += sigm(fr4.z+u2f)*h2;
          gv.w += sigm(fr4.w+u3 )*h3;
        }
      }
      *(float4*)&SH[lrow][c] = sv;
      uint2 p;
      p.x = ((unsigned int)(unsigned short)f2bf_s(gv.y)<<16) | (unsigned short)f2bf_s(gv.x);
      p.y = ((unsigned int)(unsigned short)f2bf_s(gv.w)<<16) | (unsigned short)f2bf_s(gv.z);
      *(uint2*)&SG[lrow][c] = p;
    }
  }
  __syncthreads();

  // ---- Phase B: GRU dual GEMM from LDS ----
  const int r0l = lane&15, r1l = r0l+16;
  const int r0 = rbase + r0l, r1 = rbase + r1l;
  f32x4 zero = {0.f,0.f,0.f,0.f};
  f32x4 accz[2][4], acch[2][4];
  #pragma unroll
  for (int rf=0;rf<2;rf++)
    #pragma unroll
    for (int t=0;t<4;t++){ accz[rf][t]=zero; acch[rf][t]=zero; }

  PRIO_HI;
  for (int kc=0;kc<8;kc++){
    bf16x8 a0h, a0l, a1h, a1l;
    build_a(&SH[r0l][kc*32+koff], a0h, a0l);
    build_a(&SH[r1l][kc*32+koff], a1h, a1l);
    bf16x8 s0 = *(const bf16x8*)&SG[r0l][kc*32+koff];
    bf16x8 s1 = *(const bf16x8*)&SG[r1l][kc*32+koff];
    #pragma unroll
    for (int t=0;t<4;t++){
      const short* pz = Bz + (((kc<<4)+(wc<<2)+t)<<10) + (lane<<4);
      const short* ph = Bh + (((kc<<4)+(wc<<2)+t)<<10) + (lane<<4);
      bf16x8 bzh = *(const bf16x8*)pz;
      bf16x8 bzl = *(const bf16x8*)(pz+8);
      bf16x8 bhh = *(const bf16x8*)ph;
      bf16x8 bhl = *(const bf16x8*)(ph+8);
      accz[0][t]=MFMA(a0h,bzh,accz[0][t],0,0,0);
      accz[1][t]=MFMA(a1h,bzh,accz[1][t],0,0,0);
      accz[0][t]=MFMA(a0l,bzh,accz[0][t],0,0,0);
      accz[1][t]=MFMA(a1l,bzh,accz[1][t],0,0,0);
      accz[0][t]=MFMA(a0h,bzl,accz[0][t],0,0,0);
      accz[1][t]=MFMA(a1h,bzl,accz[1][t],0,0,0);
      acch[0][t]=MFMA(s0,bhh,acch[0][t],0,0,0);
      acch[1][t]=MFMA(s1,bhh,acch[1][t],0,0,0);
      acch[0][t]=MFMA(s0,bhl,acch[0][t],0,0,0);
      acch[1][t]=MFMA(s1,bhl,acch[1][t],0,0,0);
    }
  }

  if (GEXT){
    int h0a=-1,h0b=-1,h0c=-1,h1a=-1,h1b=-1,h1c=-1;
    if (r0<M){ h0a=aidx[r0]; h0b=40+gfm[(size_t)r0*4+2]; h0c=44+gfm[(size_t)r0*4+3]; }
    if (r1<M){ h1a=aidx[r1]; h1b=40+gfm[(size_t)r1*4+2]; h1c=44+gfm[(size_t)r1*4+3]; }
    #pragma unroll
    for (int e=0;e<2;e++){
      bf16x8 ax0, ax1;
      #pragma unroll
      for (int j=0;j<8;j++){
        int d = e*32 + koff + j;
        ax0[j] = (d==h0a||d==h0b||d==h0c) ? (short)0x3F80 : (short)0;
        ax1[j] = (d==h1a||d==h1b||d==h1c) ? (short)0x3F80 : (short)0;
      }
      #pragma unroll
      for (int t=0;t<4;t++){
        const short* pe = Bze + (((e<<4)+(wc<<2)+t)<<10) + (lane<<4);
        const short* qe = Bhe + (((e<<4)+(wc<<2)+t)<<10) + (lane<<4);
        bf16x8 bzeh = *(const bf16x8*)pe;
        bf16x8 bzel = *(const bf16x8*)(pe+8);
        bf16x8 bheh = *(const bf16x8*)qe;
        bf16x8 bhel = *(const bf16x8*)(qe+8);
        accz[0][t]=MFMA(ax0,bzeh,accz[0][t],0,0,0);
        accz[1][t]=MFMA(ax1,bzeh,accz[1][t],0,0,0);
        accz[0][t]=MFMA(ax0,bzel,accz[0][t],0,0,0);
        accz[1][t]=MFMA(ax1,bzel,accz[1][t],0,0,0);
        acch[0][t]=MFMA(ax0,bheh,acch[0][t],0,0,0);
        acch[1][t]=MFMA(ax1,bheh,acch[1][t],0,0,0);
        acch[0][t]=MFMA(ax0,bhel,acch[0][t],0,0,0);
        acch[1][t]=MFMA(ax1,bhel,acch[1][t],0,0,0);
      }
    }
  }
  PRIO_LO;

  __syncthreads();   // all SG (sumgh) reads done before epilogue overwrites it

  // ---- Phase C: epilogue (per-row indices hoisted for the i/t path) ----
  const int rr = (lane>>4)<<2;
  const int cl = lane&15;
  unsigned short hreg[32];
  int src8[8], pos8[8];
  if (!GEXT){
    #pragma unroll
    for (int rf=0;rf<2;rf++)
      #pragma unroll
      for (int r=0;r<4;r++){
        int m = rbase + rr + rf*16 + r;
        int mm = (m<M)? m : 0;
        src8[rf*4+r] = fz.didx [(size_t)mm*fz.dstride];
        pos8[rf*4+r] = fz.oidx0[(size_t)mm*fz.os0] + fz.oo0;
      }
  }
  #pragma unroll
  for (int rf=0;rf<2;rf++)
    #pragma unroll
    for (int t=0;t<4;t++){
      int col = (((wc<<2)+t)<<4) + cl;
      float fzb=0.f, fhb=0.f;
      if (GEXT){ fzb = bzb[col]; fhb = bhb[col]; }
      #pragma unroll
      for (int r=0;r<4;r++){
        int lrow = rr + rf*16 + r;
        int m = rbase + lrow;
        float v = 0.f;
        if (m<M){
          float fzv, fhv;
          if (GEXT){ fzv = fzb; fhv = fhb; }
          else {
            int i8 = rf*4+r;
            size_t so = (size_t)src8[i8]*256 + col;
            size_t po = (size_t)pos8[i8]*256 + col;
            fzv = fz.bias[col] + fz.dtab[so] + fz.otab[po];
            fhv = fh.bias[col] + fh.dtab[so] + fh.otab[po];
          }
          float z   = sigm  (accz[rf][t][r] + fzv);
          float pre = tanh_f(acch[rf][t][r] + fhv);
          float sh  = SH[lrow][col];
          v = (m==0) ? 0.f : ((1.f-z)*sh + z*pre);
          if (!DO_HU) houtF[(size_t)m*256+col] = v;
        }
        if (DO_HU){
          SG[lrow][col] = f2bf_s(v);
          hreg[(((rf<<2)+t)<<2)+r] = __half_as_ushort(__float2half(v));
        }
      }
    }

  // ---- Phase D: hU = bf16(h) @ Ur; emit packed record ----
  if (DO_HU){
    __syncthreads();
    f32x4 acc[2][4];
    #pragma unroll
    for (int rf=0;rf<2;rf++)
      #pragma unroll
      for (int t=0;t<4;t++) acc[rf][t]=zero;
    PRIO_HI;
    for (int kc=0;kc<8;kc++){
      bf16x8 a0 = *(const bf16x8*)&SG[r0l][kc*32+koff];
      bf16x8 a1 = *(const bf16x8*)&SG[r1l][kc*32+koff];
      #pragma unroll
      for (int t=0;t<4;t++){
        const short* p = Bu + (((kc<<4)+(wc<<2)+t)<<10) + (lane<<4);
        bf16x8 bh = *(const bf16x8*)p;
        bf16x8 bl = *(const bf16x8*)(p+8);
        acc[0][t]=MFMA(a0,bh,acc[0][t],0,0,0);
        acc[1][t]=MFMA(a1,bh,acc[1][t],0,0,0);
        acc[0][t]=MFMA(a0,bl,acc[0][t],0,0,0);
        acc[1][t]=MFMA(a1,bl,acc[1][t],0,0,0);
      }
    }
    PRIO_LO;
    #pragma unroll
    for (int rf=0;rf<2;rf++)
      #pragma unroll
      for (int t=0;t<4;t++){
        int col = (((wc<<2)+t)<<4) + cl;
        #pragma unroll
        for (int r=0;r<4;r++){
          int m = rbase + rr + rf*16 + r;
          if (m<M){
            unsigned int hw = hreg[(((rf<<2)+t)<<2)+r];
            unsigned int uw = (unsigned short)f2bf_s(acc[rf][t][r]);
            recout[(size_t)m*256+col] = (hw<<16) | uw;
          }
        }
      }
  }
}

// ---------------------------------------------------------------------------
// Vector GEMM kept only for the tiny Wroot (M=256, tanh epilogue).
// ---------------------------------------------------------------------------
template<int NG, int MODE>
__global__ __launch_bounds__(256)
void gemm256(const float* __restrict__ A1, const float* __restrict__ B1,
             const float* __restrict__ A2, const float* __restrict__ B2,
             float* __restrict__ Cf, int M, Feat f1, int mask0)
{
  __shared__ float As[NG][16][36];
  __shared__ float Bs[NG][16][260];
  const int tid = threadIdx.x;
  const int bm = blockIdx.x<<5;
  const int tm = (tid>>5)<<2;
  const int c0 = (tid&31)<<2;

  float acc[NG][4][8];
  #pragma unroll
  for (int g=0;g<NG;g++)
    #pragma unroll
    for (int i=0;i<4;i++)
      #pragma unroll
      for (int j=0;j<8;j++) acc[g][i][j]=0.f;

  const int t7  = tid & 127;
  const int alm = t7>>2;
  const int alk = (t7&3)<<2;
  const int arow = bm + alm;
  const int amat = (NG==2)? (tid>>7) : 0;
  const bool astage = (NG==2) || (tid<128);

  for (int k0=0;k0<256;k0+=16){
    float a0=0,a1=0,a2=0,a3=0;
    if (astage && arow<M){
      const float* src = (amat==0)? A1 : A2;
      float4 v = *(const float4*)(src + (size_t)arow*256 + k0 + alk);
      a0=v.x; a1=v.y; a2=v.z; a3=v.w;
    }
    float4 breg[NG][4];
    #pragma unroll
    for (int g=0; g<NG; g++){
      const float* B = (g==0)? B1 : B2;
      #pragma unroll
      for (int j=0;j<4;j++){
        int slot = tid + 256*j;
        int kb = slot>>6, nb = (slot&63)<<2;
        breg[g][j] = *(const float4*)(B + (size_t)(k0+kb)*256 + nb);
      }
    }
    __syncthreads();
    if (astage){
      As[amat][alk+0][alm]=a0; As[amat][alk+1][alm]=a1;
      As[amat][alk+2][alm]=a2; As[amat][alk+3][alm]=a3;
    }
    #pragma unroll
    for (int g=0; g<NG; g++){
      #pragma unroll
      for (int j=0;j<4;j++){
        int slot = tid + 256*j;
        int kb = slot>>6, nb = (slot&63)<<2;
        *(float4*)&Bs[g][kb][nb] = breg[g][j];
      }
    }
    __syncthreads();
    #pragma unroll
    for (int k=0;k<16;k++){
      #pragma unroll
      for (int g=0;g<NG;g++){
        float4 av = *(const float4*)&As[g][k][tm];
        float4 b0 = *(const float4*)&Bs[g][k][c0];
        float4 b1 = *(const float4*)&Bs[g][k][c0+128];
        float a_[4]={av.x,av.y,av.z,av.w};
        float b_[8]={b0.x,b0.y,b0.z,b0.w,b1.x,b1.y,b1.z,b1.w};
        #pragma unroll
        for (int i=0;i<4;i++)
          #pragma unroll
          for (int j=0;j<8;j++)
            acc[g][i][j] = fmaf(a_[i], b_[j], acc[g][i][j]);
      }
    }
  }

  #pragma unroll
  for (int i=0;i<4;i++){
    int m = bm + tm + i;
    if (m >= M) continue;
    #pragma unroll
    for (int half=0; half<2; half++){
      int c = c0 + half*128;
      float4 r;
      float* rr = &r.x;
      float4 ft = feat_eval4(f1, m, c);
      float fv[4]={ft.x,ft.y,ft.z,ft.w};
      #pragma unroll
      for (int j=0;j<4;j++){
        float s = acc[0][i][half*4+j] + (NG>1?acc[1][i][half*4+j]:0.f) + fv[j];
        float v = (MODE==1)? fmaxf(s,0.f) : tanhf(s);
        if (MODE==1 && mask0 && m==0) v = 0.f;
        rr[j] = v;
      }
      *(float4*)(Cf + (size_t)m*256+c) = r;
    }
  }
}

// ---------------------------------------------------------------------------
extern "C" void kernel_launch(void* const* d_in, const int* in_sizes, int n_in,
                              void* d_out, int out_size, void* d_ws, size_t ws_size,
                              hipStream_t stream)
{
  const int* t_fnode  = (const int*)d_in[0];
  const int* t_fmess  = (const int*)d_in[1];
  const int* t_agraph = (const int*)d_in[2];
  const int* t_bgraph = (const int*)d_in[3];
  const int* t_cgraph = (const int*)d_in[4];
  const int* g_fnode  = (const int*)d_in[5];
  const int* g_fmess  = (const int*)d_in[6];
  const int* g_agraph = (const int*)d_in[7];
  const int* g_bgraph = (const int*)d_in[8];
  const int* roots    = (const int*)d_in[9];
  const float* E_c     = (const float*)d_in[10];
  const float* E_i     = (const float*)d_in[11];
  const float* Wc_w    = (const float*)d_in[12];
  const float* Wc_b    = (const float*)d_in[13];
  const float* Wi_w    = (const float*)d_in[14];
  const float* Wi_b    = (const float*)d_in[15];
  const float* Wroot_w = (const float*)d_in[16];
  const float* Wroot_b = (const float*)d_in[17];
  const float* t_Wo_w  = (const float*)d_in[18];
  const float* t_Wo_b  = (const float*)d_in[19];
  const float* t_Wz_w  = (const float*)d_in[20];
  const float* t_Wz_b  = (const float*)d_in[21];
  const float* t_Wr_w  = (const float*)d_in[22];
  const float* t_Ur_w  = (const float*)d_in[23];
  const float* t_Ur_b  = (const float*)d_in[24];
  const float* t_Wh_w  = (const float*)d_in[25];
  const float* t_Wh_b  = (const float*)d_in[26];
  const float* i_Wo_w  = (const float*)d_in[27];
  const float* i_Wo_b  = (const float*)d_in[28];
  const float* i_Wz_w  = (const float*)d_in[29];
  const float* i_Wz_b  = (const float*)d_in[30];
  const float* i_Wr_w  = (const float*)d_in[31];
  const float* i_Ur_w  = (const float*)d_in[32];
  const float* i_Ur_b  = (const float*)d_in[33];
  const float* i_Wh_w  = (const float*)d_in[34];
  const float* i_Wh_b  = (const float*)d_in[35];
  const float* g_Wo_w  = (const float*)d_in[36];
  const float* g_Wo_b  = (const float*)d_in[37];
  const float* g_Wz_w  = (const float*)d_in[38];
  const float* g_Wz_b  = (const float*)d_in[39];
  const float* g_Wr_w  = (const float*)d_in[40];
  const float* g_Ur_w  = (const float*)d_in[41];
  const float* g_Ur_b  = (const float*)d_in[42];
  const float* g_Wh_w  = (const float*)d_in[43];
  const float* g_Wh_b  = (const float*)d_in[44];

  float* out        = (float*)d_out;
  float* out_hroot  = out;
  float* out_htree  = out + (size_t)65536;
  float* out_hinter = out + (size_t)65536 + 2048000;
  float* out_hatom  = out + (size_t)65536 + 2048000 + 2048000;

  // ---- workspace (~162.3 MB) ------------------------------------------------
  char* base = (char*)d_ws;
  int*   aidx  = (int*)base;                               // 262144 B reserved
  short* SP    = (short*)(base + 262144);                  // plane region (8 MB)
  float* W0    = (float*)(base + 262144 + 8388608);        // f32 h + scratch (51.2MB)
  unsigned int* R0 = (unsigned int*)(W0 + (size_t)12800000);   // packed rec A
  unsigned int* R1 = R0 + (size_t)12800000;                    // packed rec B
  float* R0f = (float*)R0;
  float* R1f = (float*)R1;

  auto GP = [&](int i)->short* { return SP + (size_t)i*131072; };
  short* EZ = SP + (size_t)9*131072;
  short* EH = EZ + 32768;
  auto HP = [&](int j)->short* { return EH + 32768 + (size_t)j*131072; };
  short* P2 = EH + 32768 + (size_t)6*131072;
  auto PP = [&](int j)->short* { return P2 + (size_t)j*131072; };

  // scratch sub-buffers (lifetimes: records R0/R1 dead outside GRU loops;
  // W0 rows >=16000 never touched by i/t GRUs)
  float* neibG    = R0f;                      // 25000 rows (post g-GRU)
  float* hatom    = R1f;                      // 25000 rows (consumed pre I-GRU)
  float* neib_t   = R0f;                      // 8000 (consumed pre I-GRU)
  float* hn_i     = W0 + (size_t)16000*256;   // 8000 (alive through I Wo)
  float* hnWz     = W0 + (size_t)24000*256;   // 8000
  float* hnWr     = W0 + (size_t)32000*256;   // 8000
  float* hnWh     = W0 + (size_t)40000*256;   // 8000 (ends 48000 <= 50000)
  float* nei_i    = R0f;                      // 8000 (post I-GRU)
  float* hinter   = R1f;                      // 8000 (consumed by T prep)
  float* hn_t     = W0 + (size_t)16000*256;   // 8000 (overwrites dead hn_i)
  float* nei_t    = R0f;                      // 8000 (post T-GRU)
  float* hn_roots = R1f;                      // 256 (hinter dead after T prep)
  float* nei_root = R1f + (size_t)256*256;    // 256

  (void)in_sizes; (void)n_in; (void)out_size; (void)ws_size;

  // ---- weight split/swizzle: one batched launch ----------------------------
  SJobs js;
  js.j[0]  = { g_Ur_w,                    GP(0), 256, 0 };
  js.j[1]  = { g_Wz_w + (size_t)64*256,   GP(1), 256, 0 };
  js.j[2]  = { g_Wh_w + (size_t)64*256,   GP(2), 256, 0 };
  js.j[3]  = { i_Ur_w,                    GP(3), 256, 0 };
  js.j[4]  = { i_Wz_w + (size_t)276*256,  GP(4), 256, 0 };
  js.j[5]  = { i_Wh_w + (size_t)276*256,  GP(5), 256, 0 };
  js.j[6]  = { t_Ur_w,                    GP(6), 256, 0 };
  js.j[7]  = { t_Wz_w + (size_t)276*256,  GP(7), 256, 0 };
  js.j[8]  = { t_Wh_w + (size_t)276*256,  GP(8), 256, 0 };
  js.j[9]  = { g_Wz_w,                    EZ,     64, 0 };
  js.j[10] = { g_Wh_w,                    EH,     64, 0 };
  js.j[11] = { i_Wz_w,                    HP(0), 256, 0 };
  js.j[12] = { i_Wr_w,                    HP(1), 256, 0 };
  js.j[13] = { i_Wh_w,                    HP(2), 256, 0 };
  js.j[14] = { t_Wz_w,                    HP(3), 256, 0 };
  js.j[15] = { t_Wr_w,                    HP(4), 256, 0 };
  js.j[16] = { t_Wh_w,                    HP(5), 256, 0 };
  js.j[17] = { Wi_w,                      PP(0), 256, 0 };
  js.j[18] = { Wi_w + (size_t)256*256,    PP(1), 256, 0 };
  js.j[19] = { Wc_w,                      PP(2), 256, 0 };
  js.j[20] = { Wc_w + (size_t)256*256,    PP(3), 256, 0 };
  js.j[21] = { i_Wo_w,                    PP(4), 256, 0 };
  js.j[22] = { i_Wo_w + (size_t)256*256,  PP(5), 256, 0 };
  js.j[23] = { t_Wo_w,                    PP(6), 256, 0 };
  js.j[24] = { t_Wo_w + (size_t)256*256,  PP(7), 256, 0 };
  js.j[25] = { g_Wo_w + (size_t)40*256,   PP(8), 256, 0 };
  k_splitw_b<<<dim3(256,26),256,0,stream>>>(js);

  // ---- feature descriptors -------------------------------------------------
  Feat fzg{}; fzg.otab=g_Wz_w; fzg.oidx0=aidx;      fzg.os0=1; fzg.oo0=0;
              fzg.oidx1=g_fmess+2; fzg.os1=4; fzg.oo1=40;
              fzg.oidx2=g_fmess+3; fzg.os2=4; fzg.oo2=44; fzg.bias=g_Wz_b;
  Feat frg = fzg; frg.otab=g_Wr_w; frg.bias=g_Ur_b;
  Feat fhg = fzg; fhg.otab=g_Wh_w; fhg.bias=g_Wh_b;

  Feat fzi{}; fzi.dtab=hnWz; fzi.didx=t_fmess; fzi.dstride=3;
              fzi.otab=i_Wz_w; fzi.oidx0=t_fmess+2; fzi.os0=3; fzi.oo0=256; fzi.bias=i_Wz_b;
  Feat fri = fzi; fri.dtab=hnWr; fri.otab=i_Wr_w; fri.bias=i_Ur_b;
  Feat fhi = fzi; fhi.dtab=hnWh; fhi.otab=i_Wh_w; fhi.bias=i_Wh_b;

  Feat fzt = fzi; fzt.otab=t_Wz_w; fzt.bias=t_Wz_b;
  Feat frt = fri; frt.otab=t_Wr_w; frt.bias=t_Ur_b;
  Feat fht = fhi; fht.otab=t_Wh_w; fht.bias=t_Wh_b;

  Feat fnone{};

  // ---- GRU driver: step1+hU(rec), 3x fused rec->rec, final rec->f32 --------
  auto run_gru = [&](int M, const int* bgraph, int p, bool gext,
                     Feat fz, Feat fr, Feat fh)->float* {
    int gb32 = (M+31)/32;
    const short* Bu = GP(p*3+0);
    const short* Bz = GP(p*3+1);
    const short* Bh = GP(p*3+2);
    k_step1hu<<<gb32,256,0,stream>>>(fz, fh, Bu, R0, M);
    unsigned int* rA = R0;
    unsigned int* rB = R1;
    for (int d=0; d<4; ++d){
      if (d<3){
        if (gext)
          mfma_gg<1,1><<<gb32,256,0,stream>>>(rA, bgraph, fr, Bz, Bh,
              EZ, EH, aidx, g_fmess, g_Wz_b, g_Wh_b, fnone, fnone, Bu, rB, nullptr, M);
        else
          mfma_gg<0,1><<<gb32,256,0,stream>>>(rA, bgraph, fr, Bz, Bh,
              nullptr,nullptr,nullptr,nullptr,nullptr,nullptr, fz, fh, Bu, rB, nullptr, M);
      } else {
        if (gext)
          mfma_gg<1,0><<<gb32,256,0,stream>>>(rA, bgraph, fr, Bz, Bh,
              EZ, EH, aidx, g_fmess, g_Wz_b, g_Wh_b, fnone, fnone, nullptr, nullptr, W0, M);
        else
          mfma_gg<0,0><<<gb32,256,0,stream>>>(rA, bgraph, fr, Bz, Bh,
              nullptr,nullptr,nullptr,nullptr,nullptr,nullptr, fz, fh, nullptr, nullptr, W0, M);
      }
      unsigned int* t=rA; rA=rB; rB=t;
    }
    return W0;
  };

  // ==== Phase G: atom graph MPN ============================================
  k_aidx<<<(MA_+255)/256,256,0,stream>>>(g_fnode, g_fmess, aidx, MA_);
  float* hg = run_gru(MA_, g_bgraph, 0, true, fzg, frg, fhg);
  k_gsum4<<<(NA_+3)/4,256,0,stream>>>(hg, g_agraph, nullptr, 6, 6, neibG, NA_);
  Feat fWo{}; fWo.otab=g_Wo_w; fWo.oidx0=g_fnode; fWo.os0=1; fWo.oo0=0; fWo.bias=g_Wo_b;
  mfma_proj<1><<<(NA_+31)/32,256,0,stream>>>(neibG, nullptr, 1, nullptr,
      PP(8), nullptr, hatom, out_hatom, fWo, 1, NA_);

  // ==== Phase I prep ========================================================
  k_gsum4<<<(NT_+3)/4,256,0,stream>>>(hatom, t_cgraph, nullptr, 12, 12, neib_t, NT_);
  Feat fbWi{}; fbWi.bias=Wi_b;
  mfma_proj<2><<<NT_/32,256,0,stream>>>(E_i, t_fnode+1, 2, neib_t,
      PP(0), PP(1), hn_i, nullptr, fbWi, 0, NT_);
  mfma_mm<<<NT_/32,256,0,stream>>>(hn_i, HP(0), hnWz, NT_);
  mfma_mm<<<NT_/32,256,0,stream>>>(hn_i, HP(1), hnWr, NT_);
  mfma_mm<<<NT_/32,256,0,stream>>>(hn_i, HP(2), hnWh, NT_);

  // ==== Phase I GRU =========================================================
  float* hi = run_gru(MT_, t_bgraph, 1, false, fzi, fri, fhi);
  k_gsum4<<<(NT_+3)/4,256,0,stream>>>(hi, t_agraph, nullptr, 6, 6, nei_i, NT_);
  Feat fbWoi{}; fbWoi.bias=i_Wo_b;
  mfma_proj<2><<<NT_/32,256,0,stream>>>(hn_i, nullptr, 1, nei_i,
      PP(4), PP(5), hinter, out_hinter, fbWoi, 1, NT_);

  // ==== Phase T prep ========================================================
  Feat fbWc{}; fbWc.bias=Wc_b;
  mfma_proj<2><<<NT_/32,256,0,stream>>>(E_c, t_fnode, 2, hinter,
      PP(2), PP(3), hn_t, nullptr, fbWc, 0, NT_);
  mfma_mm<<<NT_/32,256,0,stream>>>(hn_t, HP(3), hnWz, NT_);
  mfma_mm<<<NT_/32,256,0,stream>>>(hn_t, HP(4), hnWr, NT_);
  mfma_mm<<<NT_/32,256,0,stream>>>(hn_t, HP(5), hnWh, NT_);

  // ==== Phase T GRU =========================================================
  float* ht = run_gru(MT_, t_bgraph, 2, false, fzt, frt, fht);
  k_gsum4<<<(NT_+3)/4,256,0,stream>>>(ht, t_agraph, nullptr, 6, 6, nei_t, NT_);
  Feat fbWot{}; fbWot.bias=t_Wo_b;
  mfma_proj<2><<<NT_/32,256,0,stream>>>(hn_t, nullptr, 1, nei_t,
      PP(6), PP(7), out_htree, nullptr, fbWot, 1, NT_);

  // ==== Root ================================================================
  k_gsum4<<<(NROOT_+3)/4,256,0,stream>>>(hn_t, roots, nullptr, 1, 1, hn_roots, NROOT_);
  k_gsum4<<<(NROOT_+3)/4,256,0,stream>>>(ht, t_agraph, roots, 6, 6, nei_root, NROOT_);
  Feat fbWr{}; fbWr.bias=Wroot_b;
  gemm256<2,2><<<NROOT_/32,256,0,stream>>>(hn_roots, Wroot_w, nei_root,
      Wroot_w + (size_t)256*256, out_hroot, NROOT_, fbWr, 0);
}